// Round 1
// baseline (2254.576 us; speedup 1.0000x reference)
//
#include <hip/hip_runtime.h>

#define HH 512
#define WW 512
#define BB 8
#define IMG (HH*WW)
#define NTOT (BB*IMG)

typedef float f32x4 __attribute__((ext_vector_type(4)));
typedef short short8 __attribute__((ext_vector_type(8)));
typedef short short4s __attribute__((ext_vector_type(4)));

__device__ inline ushort f2bf(float f) {
  unsigned u = __float_as_uint(f);
  u += 0x7fffu + ((u >> 16) & 1u);
  return (ushort)(u >> 16);
}
__device__ inline float bf2f_lo(unsigned u) { return __uint_as_float((u & 0xffffu) << 16); }
__device__ inline float bf2f_hi(unsigned u) { return __uint_as_float(u & 0xffff0000u); }

__device__ inline void atomic_block_sum(float part, float* red, float* dst) {
  for (int off = 32; off > 0; off >>= 1) part += __shfl_down(part, off, 64);
  int lane = threadIdx.x & 63, w = threadIdx.x >> 6;
  if (lane == 0) red[w] = part;
  __syncthreads();
  if (threadIdx.x == 0) atomicAdd(dst, red[0] + red[1] + red[2] + red[3]);
}

// ---------------- G = autocorr(Ka) + mu * sum_c autocorr(Kw_c), 9x9 ----------------
__global__ void k_prep(const float* __restrict__ Ka, const float* __restrict__ Kw,
                       const float* __restrict__ miu, float* __restrict__ G) {
  int t = threadIdx.x;
  if (t >= 81) return;
  int oy = t / 9 - 4, ox = t % 9 - 4;
  float mu = miu[0];
  float ga = 0.f;
  for (int dy = 0; dy < 5; dy++)
    for (int dx = 0; dx < 5; dx++) {
      int ey = dy + oy, ex = dx + ox;
      if (ey >= 0 && ey < 5 && ex >= 0 && ex < 5) ga += Ka[dy*5+dx] * Ka[ey*5+ex];
    }
  float gw = 0.f;
  if (oy >= -2 && oy <= 2 && ox >= -2 && ox <= 2) {
    for (int ch = 0; ch < 4; ch++)
      for (int dy = 0; dy < 3; dy++)
        for (int dx = 0; dx < 3; dx++) {
          int ey = dy + oy, ex = dx + ox;
          if (ey >= 0 && ey < 3 && ex >= 0 && ex < 3)
            gw += Kw[ch*9 + dy*3+dx] * Kw[ch*9 + ey*3+ex];
        }
  }
  G[t] = ga + mu * gw;
}

// ---------------- fused CNN: xk = cnn(x) -------------------------------------------
__launch_bounds__(512, 4)
__global__ void k_cnn(const float* __restrict__ x,
                      const float* __restrict__ W1, const float* __restrict__ b1,
                      const float* __restrict__ W2, const float* __restrict__ b2,
                      const float* __restrict__ W3, const float* __restrict__ b3,
                      float* __restrict__ xk) {
  __shared__ __align__(16) float  xs[22][23];
  __shared__ __align__(16) ushort h1s[22][712];   // 22 px * 32 ch + 8 pad (bf16)
  __shared__ __align__(16) ushort h2s[20][648];   // 20 px * 32 ch + 8 pad
  __shared__ __align__(16) ushort w2a[9216];      // A-frags: [(t*2+h)*64+l]*8+j
  __shared__ float w1s[288], b1s[32], b2s[32], w3s[288];

  const int tid = threadIdx.x;
  const int bimg = blockIdx.z;
  const int oy0 = blockIdx.y * 16, ox0 = blockIdx.x * 16;
  const float* xim = x + (size_t)bimg * IMG;

  for (int i = tid; i < 288; i += 512) { w1s[i] = W1[i]; w3s[i] = W3[i]; }
  if (tid < 32) { b1s[tid] = b1[tid]; b2s[tid] = b2[tid]; }
  for (int i = tid; i < 9216; i += 512) {
    int j = i & 7;
    int l = (i >> 3) & 63;
    int th = i >> 9;           // 0..17
    int t5 = th >> 1, hh = th & 1;
    int co = 16*hh + (l & 15);
    int ci = 8*(l >> 4) + j;
    w2a[i] = f2bf(W2[(co*32 + ci)*9 + t5]);
  }
  for (int i = tid; i < 484; i += 512) {
    int y = i / 22, xx = i % 22;
    int gy = oy0 + y - 3, gx = ox0 + xx - 3;
    float v = 0.f;
    if (gy >= 0 && gy < HH && gx >= 0 && gx < WW) v = xim[gy*WW + gx];
    xs[y][xx] = v;
  }
  __syncthreads();

  // conv1 -> h1 bf16 (zero outside image: SAME-pad semantics for conv2)
  for (int i = tid; i < 484; i += 512) {
    int y = i / 22, xx = i % 22;
    int gy = oy0 + y - 2, gx = ox0 + xx - 2;
    bool valid = (y < 20) && (xx < 20) && (gy >= 0) && (gy < HH) && (gx >= 0) && (gx < WW);
    uint4 pack[4];
    if (valid) {
      float xv[9];
      #pragma unroll
      for (int ky = 0; ky < 3; ky++)
        #pragma unroll
        for (int kx = 0; kx < 3; kx++) xv[ky*3+kx] = xs[y+ky][xx+kx];
      #pragma unroll
      for (int oc8 = 0; oc8 < 4; oc8++) {
        unsigned pk[4];
        #pragma unroll
        for (int p2 = 0; p2 < 4; p2++) {
          int ci = oc8*8 + p2*2;
          float a = b1s[ci];
          #pragma unroll
          for (int k = 0; k < 9; k++) a = fmaf(w1s[ci*9+k], xv[k], a);
          a = fmaxf(a, 0.f);
          float b_ = b1s[ci+1];
          #pragma unroll
          for (int k = 0; k < 9; k++) b_ = fmaf(w1s[(ci+1)*9+k], xv[k], b_);
          b_ = fmaxf(b_, 0.f);
          pk[p2] = (unsigned)f2bf(a) | ((unsigned)f2bf(b_) << 16);
        }
        pack[oc8] = make_uint4(pk[0], pk[1], pk[2], pk[3]);
      }
    } else {
      pack[0] = pack[1] = pack[2] = pack[3] = make_uint4(0,0,0,0);
    }
    ushort* dst = &h1s[y][xx*32];
    #pragma unroll
    for (int oc8 = 0; oc8 < 4; oc8++) *(uint4*)(dst + oc8*8) = pack[oc8];
  }
  __syncthreads();

  // conv2 via MFMA 16x16x32 bf16
  const int wv = tid >> 6, lane = tid & 63;
  const int nn = lane & 15, kg = lane >> 4;
  const int py = nn >> 2, px = nn & 3;
  for (int pb = wv; pb < 25; pb += 8) {
    const int pby = (pb / 5) * 4, pbx = (pb % 5) * 4;
    f32x4 accA = {0.f,0.f,0.f,0.f}, accB = {0.f,0.f,0.f,0.f};
    #pragma unroll
    for (int t5 = 0; t5 < 9; t5++) {
      const int ky = t5 / 3, kx = t5 % 3;
      const short8 bfr = *(const short8*)&h1s[pby + py + ky][(pbx + px + kx)*32 + kg*8];
      const short8 a0  = *(const short8*)&w2a[((t5*2+0)*64 + lane)*8];
      const short8 a1  = *(const short8*)&w2a[((t5*2+1)*64 + lane)*8];
      accA = __builtin_amdgcn_mfma_f32_16x16x32_bf16(a0, bfr, accA, 0, 0, 0);
      accB = __builtin_amdgcn_mfma_f32_16x16x32_bf16(a1, bfr, accB, 0, 0, 0);
    }
    const int h2y = pby + py, h2x = pbx + px;
    const int gy = oy0 + h2y - 1, gx = ox0 + h2x - 1;
    const bool inb = (gy >= 0) && (gy < HH) && (gx >= 0) && (gx < WW);
    {
      int cb = 4*kg;
      short4s s;
      #pragma unroll
      for (int j = 0; j < 4; j++) {
        float v = inb ? fmaxf(accA[j] + b2s[cb+j], 0.f) : 0.f;
        s[j] = (short)f2bf(v);
      }
      *(short4s*)&h2s[h2y][h2x*32 + cb] = s;
      cb = 16 + 4*kg;
      #pragma unroll
      for (int j = 0; j < 4; j++) {
        float v = inb ? fmaxf(accB[j] + b2s[cb+j], 0.f) : 0.f;
        s[j] = (short)f2bf(v);
      }
      *(short4s*)&h2s[h2y][h2x*32 + cb] = s;
    }
  }
  __syncthreads();

  // conv3 + residual
  if (tid < 256) {
    int oy = tid >> 4, ox = tid & 15;
    float acc = b3[0] + xs[oy+3][ox+3];
    #pragma unroll
    for (int ky = 0; ky < 3; ky++)
      #pragma unroll
      for (int kx = 0; kx < 3; kx++) {
        const ushort* hp = &h2s[oy+ky][(ox+kx)*32];
        #pragma unroll
        for (int c8 = 0; c8 < 4; c8++) {
          uint4 u = *(const uint4*)(hp + c8*8);
          unsigned uu[4] = {u.x, u.y, u.z, u.w};
          #pragma unroll
          for (int q2 = 0; q2 < 4; q2++) {
            int ci = c8*8 + q2*2;
            acc = fmaf(w3s[ci*9 + ky*3+kx],     bf2f_lo(uu[q2]), acc);
            acc = fmaf(w3s[(ci+1)*9 + ky*3+kx], bf2f_hi(uu[q2]), acc);
          }
        }
      }
    int gy = oy0 + oy, gx = ox0 + ox;
    xk[(size_t)bimg*IMG + gy*WW + gx] = acc;
  }
}

// ---------------- rhs = ATop(sino) + miu * WTop(softthresh(Wop(x))) ----------------
__launch_bounds__(256, 4)
__global__ void k_rhs(const float* __restrict__ sino, const float* __restrict__ x,
                      const float* __restrict__ laam, const float* __restrict__ miu,
                      const float* __restrict__ Ka, const float* __restrict__ Kw,
                      float* __restrict__ rhs) {
  __shared__ float xs[36][37];
  __shared__ float ss[36][37];
  __shared__ float dz[4][34][35];
  __shared__ float kas[25], kws[36];
  int tid = threadIdx.x;
  int bimg = blockIdx.z;
  int oy0 = blockIdx.y*32, ox0 = blockIdx.x*32;
  const float* xim = x + (size_t)bimg*IMG;
  const float* sim = sino + (size_t)bimg*IMG;
  if (tid < 25) kas[tid] = Ka[tid];
  if (tid < 36) kws[tid] = Kw[tid];
  float lam = laam[0], mu = miu[0];
  for (int i = tid; i < 1296; i += 256) {
    int y = i/36, xx = i%36;
    int gy = oy0 + y - 2, gx = ox0 + xx - 2;
    bool in = (gy >= 0 && gy < HH && gx >= 0 && gx < WW);
    xs[y][xx] = in ? xim[gy*WW+gx] : 0.f;
    ss[y][xx] = in ? sim[gy*WW+gx] : 0.f;
  }
  __syncthreads();
  for (int i = tid; i < 1156; i += 256) {
    int dy = i/34, dx = i%34;
    int gy = oy0 + dy - 1, gx = ox0 + dx - 1;
    bool in = (gy >= 0 && gy < HH && gx >= 0 && gx < WW);
    #pragma unroll
    for (int ch = 0; ch < 4; ch++) {
      float v = 0.f;
      if (in) {
        float wu = 0.f;
        #pragma unroll
        for (int e = 0; e < 9; e++) wu = fmaf(kws[ch*9+e], xs[dy + e/3][dx + e%3], wu);
        v = fmaxf(wu - lam, 0.f) - fmaxf(-wu - lam, 0.f);
      }
      dz[ch][dy][dx] = v;
    }
  }
  __syncthreads();
  for (int i = tid; i < 1024; i += 256) {
    int oy = i/32, ox = i%32;
    float qa = 0.f;
    #pragma unroll
    for (int d = 0; d < 25; d++) qa = fmaf(kas[d], ss[oy + 4 - d/5][ox + 4 - d%5], qa);
    float wt = 0.f;
    #pragma unroll
    for (int ch = 0; ch < 4; ch++)
      #pragma unroll
      for (int d = 0; d < 9; d++)
        wt = fmaf(kws[ch*9+d], dz[ch][oy + 2 - d/3][ox + 2 - d%3], wt);
    rhs[(size_t)bimg*IMG + (oy0+oy)*WW + ox0+ox] = qa + mu*wt;
  }
}

// ---------------- exact border evaluation of M -------------------------------------
__device__ float exact_border(const float (*ssrc)[73], int sy, int sx, int gy, int gx,
                              const float* __restrict__ Ka, const float* __restrict__ Kw,
                              float mu) {
  float qa = 0.f;
  for (int dy = 0; dy < 5; dy++)
    for (int dx = 0; dx < 5; dx++) {
      int zy = gy + 2 - dy, zx = gx + 2 - dx;
      if (zy < 0 || zy >= HH || zx < 0 || zx >= WW) continue;
      float inner = 0.f;
      for (int ey = 0; ey < 5; ey++)
        for (int ex = 0; ex < 5; ex++)
          inner = fmaf(Ka[ey*5+ex], ssrc[sy+4 + ey-dy][sx+4 + ex-dx], inner);
      qa = fmaf(Ka[dy*5+dx], inner, qa);
    }
  float qw = 0.f;
  for (int ch = 0; ch < 4; ch++)
    for (int dy = 0; dy < 3; dy++)
      for (int dx = 0; dx < 3; dx++) {
        int zy = gy + 1 - dy, zx = gx + 1 - dx;
        if (zy < 0 || zy >= HH || zx < 0 || zx >= WW) continue;
        float inner = 0.f;
        for (int ey = 0; ey < 3; ey++)
          for (int ex = 0; ex < 3; ex++)
            inner = fmaf(Kw[ch*9+ey*3+ex], ssrc[sy+4 + ey-dy][sx+4 + ex-dx], inner);
        qw = fmaf(Kw[ch*9+dy*3+dx], inner, qw);
      }
  return qa + mu*qw;
}

// ---------------- M-apply kernel (tile 32 rows x 64 cols) --------------------------
// MODE 0: src=xk, out r = M(xk)-rhs, p0 = -r, acc += <r,r>
// MODE 1: src=p,  out q = M(p),  acc += <p,q>
// MODE 2: p = -r + be*p_old (computed on the fly), write p_new, q=M(p), acc += <p,q>
template<int MODE>
__launch_bounds__(256, 4)
__global__ void k_M(const float* __restrict__ srcA, const float* __restrict__ srcB,
                    const float* __restrict__ rhs,
                    float* __restrict__ outQ, float* __restrict__ outP,
                    const float* __restrict__ G,
                    const float* __restrict__ Ka, const float* __restrict__ Kw,
                    const float* __restrict__ miu,
                    const float* __restrict__ beN, const float* __restrict__ beD,
                    float* __restrict__ acc) {
  __shared__ float ssrc[40][73];
  __shared__ float Gs[81];
  __shared__ float red[4];
  const int tid = threadIdx.x;
  const int bimg = blockIdx.z;
  const int oy0 = blockIdx.y*32, ox0 = blockIdx.x*64;
  if (tid < 81) Gs[tid] = G[tid];
  const float mu = miu[0];
  float be = 0.f;
  if (MODE == 2) be = beN[bimg] / beD[bimg];
  const float* sA = srcA + (size_t)bimg*IMG;
  const float* sB = (MODE == 2) ? srcB + (size_t)bimg*IMG : nullptr;
  for (int i = tid; i < 40*72; i += 256) {
    int ly = i/72, lx = i%72;
    int gy = oy0 + ly - 4, gx = ox0 + lx - 4;
    bool in = (gy >= 0 && gy < HH && gx >= 0 && gx < WW);
    float v = 0.f;
    if (MODE == 2) {
      if (in) {
        v = -sA[gy*WW+gx] + be * sB[gy*WW+gx];
        if (ly >= 4 && ly < 36 && lx >= 4 && lx < 68)
          outP[(size_t)bimg*IMG + gy*WW + gx] = v;
      }
    } else {
      if (in) v = sA[gy*WW+gx];
    }
    ssrc[ly][lx] = v;
  }
  __syncthreads();

  const int sy = tid >> 3, sx0 = (tid & 7) * 8;
  const int gy = oy0 + sy, gx0 = ox0 + sx0;
  float accv[8];
  #pragma unroll
  for (int k = 0; k < 8; k++) accv[k] = 0.f;
  const bool rowB = (gy < 2) || (gy >= HH-2);
  const bool colB = (gx0 < 2) || (gx0+7 >= WW-2);
  if (!rowB && !colB) {
    #pragma unroll 1
    for (int oyy = 0; oyy < 9; oyy++) {
      float g[9];
      #pragma unroll
      for (int t = 0; t < 9; t++) g[t] = Gs[oyy*9+t];
      float v[16];
      #pragma unroll
      for (int t = 0; t < 16; t++) v[t] = ssrc[sy+oyy][sx0+t];
      #pragma unroll
      for (int k = 0; k < 8; k++) {
        float a = accv[k];
        #pragma unroll
        for (int t = 0; t < 9; t++) a = fmaf(g[t], v[k+t], a);
        accv[k] = a;
      }
    }
  } else {
    for (int k = 0; k < 8; k++) {
      int gx = gx0 + k;
      if (gy < 2 || gy >= HH-2 || gx < 2 || gx >= WW-2) {
        accv[k] = exact_border(ssrc, sy, sx0+k, gy, gx, Ka, Kw, mu);
      } else {
        float a = 0.f;
        for (int oyy = 0; oyy < 9; oyy++)
          for (int oxx = 0; oxx < 9; oxx++)
            a = fmaf(Gs[oyy*9+oxx], ssrc[sy+oyy][sx0+k+oxx], a);
        accv[k] = a;
      }
    }
  }

  float part = 0.f;
  if (MODE == 0) {
    #pragma unroll
    for (int k = 0; k < 8; k++) {
      size_t idx = (size_t)bimg*IMG + gy*WW + gx0 + k;
      float rv = accv[k] - rhs[idx];
      outQ[idx] = rv;
      outP[idx] = -rv;
      part += rv*rv;
    }
  } else {
    #pragma unroll
    for (int k = 0; k < 8; k++) {
      size_t idx = (size_t)bimg*IMG + gy*WW + gx0 + k;
      float pv = ssrc[sy+4][sx0+4+k];
      outQ[idx] = accv[k];
      part += pv * accv[k];
    }
  }
  atomic_block_sum(part, red, &acc[bimg]);
}

// ---------------- CG axpy update ---------------------------------------------------
__launch_bounds__(256, 8)
__global__ void k_upd(float* __restrict__ xk, float* __restrict__ r,
                      const float* __restrict__ p, const float* __restrict__ q,
                      const float* __restrict__ num, const float* __restrict__ den,
                      float* __restrict__ rtrOut) {
  __shared__ float red[4];
  const int tid = threadIdx.x;
  const int bimg = blockIdx.x >> 8;
  const size_t idx4 = (size_t)blockIdx.x * 256 + tid;
  const float al = num[bimg] / den[bimg];
  float4 xv = ((const float4*)xk)[idx4];
  float4 pv = ((const float4*)p)[idx4];
  float4 rv = ((const float4*)r)[idx4];
  float4 qv = ((const float4*)q)[idx4];
  xv.x += al*pv.x; xv.y += al*pv.y; xv.z += al*pv.z; xv.w += al*pv.w;
  rv.x += al*qv.x; rv.y += al*qv.y; rv.z += al*qv.z; rv.w += al*qv.w;
  ((float4*)xk)[idx4] = xv;
  ((float4*)r)[idx4] = rv;
  float part = rv.x*rv.x + rv.y*rv.y + rv.z*rv.z + rv.w*rv.w;
  atomic_block_sum(part, red, &rtrOut[bimg]);
}

__launch_bounds__(256, 8)
__global__ void k_final(const float* __restrict__ xk, const float* __restrict__ p,
                        const float* __restrict__ num, const float* __restrict__ den,
                        float* __restrict__ out) {
  const int tid = threadIdx.x;
  const int bimg = blockIdx.x >> 8;
  const size_t idx4 = (size_t)blockIdx.x * 256 + tid;
  const float al = num[bimg] / den[bimg];
  float4 xv = ((const float4*)xk)[idx4];
  float4 pv = ((const float4*)p)[idx4];
  float4 o;
  o.x = xv.x + al*pv.x; o.y = xv.y + al*pv.y; o.z = xv.z + al*pv.z; o.w = xv.w + al*pv.w;
  ((float4*)out)[idx4] = o;
}

extern "C" void kernel_launch(void* const* d_in, const int* in_sizes, int n_in,
                              void* d_out, int out_size, void* d_ws, size_t ws_size,
                              hipStream_t stream) {
  const float* sino = (const float*)d_in[0];
  const float* x    = (const float*)d_in[1];
  const float* laam = (const float*)d_in[2];
  const float* miu  = (const float*)d_in[3];
  const float* Kw   = (const float*)d_in[4];
  const float* Ka   = (const float*)d_in[5];
  const float* W1   = (const float*)d_in[6];
  const float* b1   = (const float*)d_in[7];
  const float* W2   = (const float*)d_in[8];
  const float* b2   = (const float*)d_in[9];
  const float* W3   = (const float*)d_in[10];
  const float* b3   = (const float*)d_in[11];

  float* ws = (float*)d_ws;
  float* xk = ws;
  float* r  = ws + (size_t)NTOT;
  float* p0 = ws + 2*(size_t)NTOT;
  float* p1 = ws + 3*(size_t)NTOT;
  float* q  = ws + 4*(size_t)NTOT;
  float* G  = ws + 5*(size_t)NTOT;
  float* accb = G + 128;
  float* den = accb;       // den[i*8 + b], i = 0..5
  float* rtr = accb + 48;  // rtr[j*8 + b], j = 0..5
  float* rhs = (float*)d_out;   // d_out doubles as rhs scratch until the end
  float* out = (float*)d_out;

  hipMemsetAsync(accb, 0, 96*sizeof(float), stream);
  k_prep<<<1, 128, 0, stream>>>(Ka, Kw, miu, G);
  k_cnn<<<dim3(32,32,8), 512, 0, stream>>>(x, W1,b1,W2,b2,W3,b3, xk);
  k_rhs<<<dim3(16,16,8), 256, 0, stream>>>(sino, x, laam, miu, Ka, Kw, rhs);

  dim3 mg(8,16,8);
  k_M<0><<<mg,256,0,stream>>>(xk, nullptr, rhs, r, p0, G, Ka, Kw, miu, nullptr, nullptr, &rtr[0]);
  // i = 0
  k_M<1><<<mg,256,0,stream>>>(p0, nullptr, nullptr, q, nullptr, G, Ka, Kw, miu, nullptr, nullptr, &den[0]);
  k_upd<<<2048,256,0,stream>>>(xk, r, p0, q, &rtr[0], &den[0], &rtr[8]);
  // i = 1..4
  float* pcur = p0; float* pnext = p1;
  for (int i = 1; i <= 4; i++) {
    k_M<2><<<mg,256,0,stream>>>(r, pcur, nullptr, q, pnext, G, Ka, Kw, miu, &rtr[8*i], &rtr[8*(i-1)], &den[8*i]);
    k_upd<<<2048,256,0,stream>>>(xk, r, pnext, q, &rtr[8*i], &den[8*i], &rtr[8*(i+1)]);
    float* t = pcur; pcur = pnext; pnext = t;
  }
  // final half step (i = 5)
  k_M<2><<<mg,256,0,stream>>>(r, pcur, nullptr, q, pnext, G, Ka, Kw, miu, &rtr[40], &rtr[32], &den[40]);
  k_final<<<2048,256,0,stream>>>(xk, pnext, &rtr[40], &den[40], out);
}

// Round 2
// 2241.204 us; speedup vs baseline: 1.0060x; 1.0060x over previous
//
#include <hip/hip_runtime.h>

#define HH 512
#define WW 512
#define BB 8
#define IMG (HH*WW)
#define NTOT (BB*IMG)

typedef float f32x4 __attribute__((ext_vector_type(4)));
typedef short short8 __attribute__((ext_vector_type(8)));
typedef short short4s __attribute__((ext_vector_type(4)));

__device__ inline ushort f2bf(float f) {
  unsigned u = __float_as_uint(f);
  u += 0x7fffu + ((u >> 16) & 1u);
  return (ushort)(u >> 16);
}
__device__ inline float bf2f_lo(unsigned u) { return __uint_as_float((u & 0xffffu) << 16); }
__device__ inline float bf2f_hi(unsigned u) { return __uint_as_float(u & 0xffff0000u); }

__device__ inline void atomic_block_sum(float part, float* red, float* dst) {
  for (int off = 32; off > 0; off >>= 1) part += __shfl_down(part, off, 64);
  int lane = threadIdx.x & 63, w = threadIdx.x >> 6;
  if (lane == 0) red[w] = part;
  __syncthreads();
  if (threadIdx.x == 0) atomicAdd(dst, red[0] + red[1] + red[2] + red[3]);
}

// ---------------- G = autocorr(Ka) + mu * sum_c autocorr(Kw_c), 9x9 ----------------
__global__ void k_prep(const float* __restrict__ Ka, const float* __restrict__ Kw,
                       const float* __restrict__ miu, float* __restrict__ G) {
  int t = threadIdx.x;
  if (t >= 81) return;
  int oy = t / 9 - 4, ox = t % 9 - 4;
  float mu = miu[0];
  float ga = 0.f;
  for (int dy = 0; dy < 5; dy++)
    for (int dx = 0; dx < 5; dx++) {
      int ey = dy + oy, ex = dx + ox;
      if (ey >= 0 && ey < 5 && ex >= 0 && ex < 5) ga += Ka[dy*5+dx] * Ka[ey*5+ex];
    }
  float gw = 0.f;
  if (oy >= -2 && oy <= 2 && ox >= -2 && ox <= 2) {
    for (int ch = 0; ch < 4; ch++)
      for (int dy = 0; dy < 3; dy++)
        for (int dx = 0; dx < 3; dx++) {
          int ey = dy + oy, ex = dx + ox;
          if (ey >= 0 && ey < 3 && ex >= 0 && ex < 3)
            gw += Kw[ch*9 + dy*3+dx] * Kw[ch*9 + ey*3+ex];
        }
  }
  G[t] = ga + mu * gw;
}

// ---------------- fused CNN: xk = cnn(x) -------------------------------------------
__launch_bounds__(512)
__global__ void k_cnn(const float* __restrict__ x,
                      const float* __restrict__ W1, const float* __restrict__ b1,
                      const float* __restrict__ W2, const float* __restrict__ b2,
                      const float* __restrict__ W3, const float* __restrict__ b3,
                      float* __restrict__ xk) {
  __shared__ __align__(16) float  xs[22][23];
  __shared__ __align__(16) ushort h1s[22][712];   // 22 px * 32 ch + 8 pad (bf16)
  __shared__ __align__(16) ushort h2s[20][648];   // 20 px * 32 ch + 8 pad
  __shared__ __align__(16) ushort w2a[9216];      // A-frags: [(t*2+h)*64+l]*8+j
  __shared__ float w1s[288], b1s[32], b2s[32], w3s[288];

  const int tid = threadIdx.x;
  const int bimg = blockIdx.z;
  const int oy0 = blockIdx.y * 16, ox0 = blockIdx.x * 16;
  const float* xim = x + (size_t)bimg * IMG;

  for (int i = tid; i < 288; i += 512) { w1s[i] = W1[i]; w3s[i] = W3[i]; }
  if (tid < 32) { b1s[tid] = b1[tid]; b2s[tid] = b2[tid]; }
  for (int i = tid; i < 9216; i += 512) {
    int j = i & 7;
    int l = (i >> 3) & 63;
    int th = i >> 9;           // 0..17
    int t5 = th >> 1, hh = th & 1;
    int co = 16*hh + (l & 15);
    int ci = 8*(l >> 4) + j;
    w2a[i] = f2bf(W2[(co*32 + ci)*9 + t5]);
  }
  for (int i = tid; i < 484; i += 512) {
    int y = i / 22, xx = i % 22;
    int gy = oy0 + y - 3, gx = ox0 + xx - 3;
    float v = 0.f;
    if (gy >= 0 && gy < HH && gx >= 0 && gx < WW) v = xim[gy*WW + gx];
    xs[y][xx] = v;
  }
  __syncthreads();

  // conv1 -> h1 bf16 (zero outside image: SAME-pad semantics for conv2)
  // store each 8-channel pack immediately: small live set, no spills
  for (int i = tid; i < 484; i += 512) {
    int y = i / 22, xx = i % 22;
    int gy = oy0 + y - 2, gx = ox0 + xx - 2;
    bool valid = (y < 20) && (xx < 20) && (gy >= 0) && (gy < HH) && (gx >= 0) && (gx < WW);
    ushort* dst = &h1s[y][xx*32];
    if (valid) {
      float xv[9];
      #pragma unroll
      for (int ky = 0; ky < 3; ky++)
        #pragma unroll
        for (int kx = 0; kx < 3; kx++) xv[ky*3+kx] = xs[y+ky][xx+kx];
      #pragma unroll
      for (int oc8 = 0; oc8 < 4; oc8++) {
        unsigned pk0, pk1, pk2, pk3;
        #pragma unroll
        for (int p2 = 0; p2 < 4; p2++) {
          int ci = oc8*8 + p2*2;
          float a = b1s[ci];
          #pragma unroll
          for (int k = 0; k < 9; k++) a = fmaf(w1s[ci*9+k], xv[k], a);
          a = fmaxf(a, 0.f);
          float b_ = b1s[ci+1];
          #pragma unroll
          for (int k = 0; k < 9; k++) b_ = fmaf(w1s[(ci+1)*9+k], xv[k], b_);
          b_ = fmaxf(b_, 0.f);
          unsigned pk = (unsigned)f2bf(a) | ((unsigned)f2bf(b_) << 16);
          if (p2 == 0) pk0 = pk; else if (p2 == 1) pk1 = pk;
          else if (p2 == 2) pk2 = pk; else pk3 = pk;
        }
        *(uint4*)(dst + oc8*8) = make_uint4(pk0, pk1, pk2, pk3);
      }
    } else {
      #pragma unroll
      for (int oc8 = 0; oc8 < 4; oc8++)
        *(uint4*)(dst + oc8*8) = make_uint4(0,0,0,0);
    }
  }
  __syncthreads();

  // conv2 via MFMA 16x16x32 bf16
  const int wv = tid >> 6, lane = tid & 63;
  const int nn = lane & 15, kg = lane >> 4;
  const int py = nn >> 2, px = nn & 3;
  for (int pb = wv; pb < 25; pb += 8) {
    const int pby = (pb / 5) * 4, pbx = (pb % 5) * 4;
    f32x4 accA = {0.f,0.f,0.f,0.f}, accB = {0.f,0.f,0.f,0.f};
    #pragma unroll
    for (int t5 = 0; t5 < 9; t5++) {
      const int ky = t5 / 3, kx = t5 % 3;
      const short8 bfr = *(const short8*)&h1s[pby + py + ky][(pbx + px + kx)*32 + kg*8];
      const short8 a0  = *(const short8*)&w2a[((t5*2+0)*64 + lane)*8];
      const short8 a1  = *(const short8*)&w2a[((t5*2+1)*64 + lane)*8];
      accA = __builtin_amdgcn_mfma_f32_16x16x32_bf16(a0, bfr, accA, 0, 0, 0);
      accB = __builtin_amdgcn_mfma_f32_16x16x32_bf16(a1, bfr, accB, 0, 0, 0);
    }
    const int h2y = pby + py, h2x = pbx + px;
    const int gy = oy0 + h2y - 1, gx = ox0 + h2x - 1;
    const bool inb = (gy >= 0) && (gy < HH) && (gx >= 0) && (gx < WW);
    {
      int cb = 4*kg;
      short4s s;
      #pragma unroll
      for (int j = 0; j < 4; j++) {
        float v = inb ? fmaxf(accA[j] + b2s[cb+j], 0.f) : 0.f;
        s[j] = (short)f2bf(v);
      }
      *(short4s*)&h2s[h2y][h2x*32 + cb] = s;
      cb = 16 + 4*kg;
      #pragma unroll
      for (int j = 0; j < 4; j++) {
        float v = inb ? fmaxf(accB[j] + b2s[cb+j], 0.f) : 0.f;
        s[j] = (short)f2bf(v);
      }
      *(short4s*)&h2s[h2y][h2x*32 + cb] = s;
    }
  }
  __syncthreads();

  // conv3 + residual
  if (tid < 256) {
    int oy = tid >> 4, ox = tid & 15;
    float acc = b3[0] + xs[oy+3][ox+3];
    #pragma unroll
    for (int ky = 0; ky < 3; ky++)
      #pragma unroll
      for (int kx = 0; kx < 3; kx++) {
        const ushort* hp = &h2s[oy+ky][(ox+kx)*32];
        #pragma unroll
        for (int c8 = 0; c8 < 4; c8++) {
          uint4 u = *(const uint4*)(hp + c8*8);
          unsigned uu0 = u.x, uu1 = u.y, uu2 = u.z, uu3 = u.w;
          int ci = c8*8;
          acc = fmaf(w3s[(ci+0)*9 + ky*3+kx], bf2f_lo(uu0), acc);
          acc = fmaf(w3s[(ci+1)*9 + ky*3+kx], bf2f_hi(uu0), acc);
          acc = fmaf(w3s[(ci+2)*9 + ky*3+kx], bf2f_lo(uu1), acc);
          acc = fmaf(w3s[(ci+3)*9 + ky*3+kx], bf2f_hi(uu1), acc);
          acc = fmaf(w3s[(ci+4)*9 + ky*3+kx], bf2f_lo(uu2), acc);
          acc = fmaf(w3s[(ci+5)*9 + ky*3+kx], bf2f_hi(uu2), acc);
          acc = fmaf(w3s[(ci+6)*9 + ky*3+kx], bf2f_lo(uu3), acc);
          acc = fmaf(w3s[(ci+7)*9 + ky*3+kx], bf2f_hi(uu3), acc);
        }
      }
    int gy = oy0 + oy, gx = ox0 + ox;
    xk[(size_t)bimg*IMG + gy*WW + gx] = acc;
  }
}

// ---------------- rhs = ATop(sino) + miu * WTop(softthresh(Wop(x))) ----------------
__launch_bounds__(256)
__global__ void k_rhs(const float* __restrict__ sino, const float* __restrict__ x,
                      const float* __restrict__ laam, const float* __restrict__ miu,
                      const float* __restrict__ Ka, const float* __restrict__ Kw,
                      float* __restrict__ rhs) {
  __shared__ float xs[36][37];
  __shared__ float ss[36][37];
  __shared__ float dz[4][34][35];
  __shared__ float kas[25], kws[36];
  int tid = threadIdx.x;
  int bimg = blockIdx.z;
  int oy0 = blockIdx.y*32, ox0 = blockIdx.x*32;
  const float* xim = x + (size_t)bimg*IMG;
  const float* sim = sino + (size_t)bimg*IMG;
  if (tid < 25) kas[tid] = Ka[tid];
  if (tid < 36) kws[tid] = Kw[tid];
  float lam = laam[0], mu = miu[0];
  for (int i = tid; i < 1296; i += 256) {
    int y = i/36, xx = i%36;
    int gy = oy0 + y - 2, gx = ox0 + xx - 2;
    bool in = (gy >= 0 && gy < HH && gx >= 0 && gx < WW);
    xs[y][xx] = in ? xim[gy*WW+gx] : 0.f;
    ss[y][xx] = in ? sim[gy*WW+gx] : 0.f;
  }
  __syncthreads();
  for (int i = tid; i < 1156; i += 256) {
    int dy = i/34, dx = i%34;
    int gy = oy0 + dy - 1, gx = ox0 + dx - 1;
    bool in = (gy >= 0 && gy < HH && gx >= 0 && gx < WW);
    #pragma unroll
    for (int ch = 0; ch < 4; ch++) {
      float v = 0.f;
      if (in) {
        float wu = 0.f;
        #pragma unroll
        for (int e = 0; e < 9; e++) wu = fmaf(kws[ch*9+e], xs[dy + e/3][dx + e%3], wu);
        v = fmaxf(wu - lam, 0.f) - fmaxf(-wu - lam, 0.f);
      }
      dz[ch][dy][dx] = v;
    }
  }
  __syncthreads();
  for (int i = tid; i < 1024; i += 256) {
    int oy = i/32, ox = i%32;
    float qa = 0.f;
    #pragma unroll
    for (int d = 0; d < 25; d++) qa = fmaf(kas[d], ss[oy + 4 - d/5][ox + 4 - d%5], qa);
    float wt = 0.f;
    #pragma unroll
    for (int ch = 0; ch < 4; ch++)
      #pragma unroll
      for (int d = 0; d < 9; d++)
        wt = fmaf(kws[ch*9+d], dz[ch][oy + 2 - d/3][ox + 2 - d%3], wt);
    rhs[(size_t)bimg*IMG + (oy0+oy)*WW + ox0+ox] = qa + mu*wt;
  }
}

// ---------------- exact border evaluation of M -------------------------------------
// noinline: keeps the huge divergent body out of the hot path's register allocation
__device__ __attribute__((noinline))
float exact_border(const float (*ssrc)[73], int sy, int sx, int gy, int gx,
                   const float* __restrict__ Ka, const float* __restrict__ Kw,
                   float mu) {
  float qa = 0.f;
  for (int dy = 0; dy < 5; dy++)
    for (int dx = 0; dx < 5; dx++) {
      int zy = gy + 2 - dy, zx = gx + 2 - dx;
      if (zy < 0 || zy >= HH || zx < 0 || zx >= WW) continue;
      float inner = 0.f;
      for (int ey = 0; ey < 5; ey++)
        for (int ex = 0; ex < 5; ex++)
          inner = fmaf(Ka[ey*5+ex], ssrc[sy+4 + ey-dy][sx+4 + ex-dx], inner);
      qa = fmaf(Ka[dy*5+dx], inner, qa);
    }
  float qw = 0.f;
  for (int ch = 0; ch < 4; ch++)
    for (int dy = 0; dy < 3; dy++)
      for (int dx = 0; dx < 3; dx++) {
        int zy = gy + 1 - dy, zx = gx + 1 - dx;
        if (zy < 0 || zy >= HH || zx < 0 || zx >= WW) continue;
        float inner = 0.f;
        for (int ey = 0; ey < 3; ey++)
          for (int ex = 0; ex < 3; ex++)
            inner = fmaf(Kw[ch*9+ey*3+ex], ssrc[sy+4 + ey-dy][sx+4 + ex-dx], inner);
        qw = fmaf(Kw[ch*9+dy*3+dx], inner, qw);
      }
  return qa + mu*qw;
}

// ---------------- M-apply kernel (tile 32 rows x 64 cols) --------------------------
// MODE 0: src=xk, out r = M(xk)-rhs, p0 = -r, acc += <r,r>
// MODE 1: src=p,  out q = M(p),  acc += <p,q>
// MODE 2: p = -r + be*p_old (computed on the fly), write p_new, q=M(p), acc += <p,q>
template<int MODE>
__launch_bounds__(256)
__global__ void k_M(const float* __restrict__ srcA, const float* __restrict__ srcB,
                    const float* __restrict__ rhs,
                    float* __restrict__ outQ, float* __restrict__ outP,
                    const float* __restrict__ G,
                    const float* __restrict__ Ka, const float* __restrict__ Kw,
                    const float* __restrict__ miu,
                    const float* __restrict__ beN, const float* __restrict__ beD,
                    float* __restrict__ acc) {
  __shared__ float ssrc[40][73];
  __shared__ float Gs[81];
  __shared__ float red[4];
  const int tid = threadIdx.x;
  const int bimg = blockIdx.z;
  const int oy0 = blockIdx.y*32, ox0 = blockIdx.x*64;
  if (tid < 81) Gs[tid] = G[tid];
  const float mu = miu[0];
  float be = 0.f;
  if (MODE == 2) be = beN[bimg] / beD[bimg];
  const float* sA = srcA + (size_t)bimg*IMG;
  const float* sB = (MODE == 2) ? srcB + (size_t)bimg*IMG : nullptr;
  for (int i = tid; i < 40*72; i += 256) {
    int ly = i/72, lx = i%72;
    int gy = oy0 + ly - 4, gx = ox0 + lx - 4;
    bool in = (gy >= 0 && gy < HH && gx >= 0 && gx < WW);
    float v = 0.f;
    if (MODE == 2) {
      if (in) {
        v = -sA[gy*WW+gx] + be * sB[gy*WW+gx];
        if (ly >= 4 && ly < 36 && lx >= 4 && lx < 68)
          outP[(size_t)bimg*IMG + gy*WW + gx] = v;
      }
    } else {
      if (in) v = sA[gy*WW+gx];
    }
    ssrc[ly][lx] = v;
  }
  __syncthreads();

  const int sy = tid >> 3, sx0 = (tid & 7) * 8;
  const int gy = oy0 + sy, gx0 = ox0 + sx0;
  float accv[8];
  #pragma unroll
  for (int k = 0; k < 8; k++) accv[k] = 0.f;
  const bool rowB = (gy < 2) || (gy >= HH-2);
  const bool colB = (gx0 < 2) || (gx0+7 >= WW-2);
  if (!rowB && !colB) {
    #pragma unroll 1
    for (int oyy = 0; oyy < 9; oyy++) {
      float g[9];
      #pragma unroll
      for (int t = 0; t < 9; t++) g[t] = Gs[oyy*9+t];
      float v[16];
      #pragma unroll
      for (int t = 0; t < 16; t++) v[t] = ssrc[sy+oyy][sx0+t];
      #pragma unroll
      for (int k = 0; k < 8; k++) {
        float a = accv[k];
        #pragma unroll
        for (int t = 0; t < 9; t++) a = fmaf(g[t], v[k+t], a);
        accv[k] = a;
      }
    }
  } else {
    // fully unrolled so accv[] stays statically indexed (rule #20: dynamic index -> scratch)
    #pragma unroll
    for (int k = 0; k < 8; k++) {
      int gx = gx0 + k;
      if (gy < 2 || gy >= HH-2 || gx < 2 || gx >= WW-2) {
        accv[k] = exact_border(ssrc, sy, sx0+k, gy, gx, Ka, Kw, mu);
      } else {
        float a = 0.f;
        #pragma unroll 1
        for (int oyy = 0; oyy < 9; oyy++)
          #pragma unroll
          for (int oxx = 0; oxx < 9; oxx++)
            a = fmaf(Gs[oyy*9+oxx], ssrc[sy+oyy][sx0+k+oxx], a);
        accv[k] = a;
      }
    }
  }

  float part = 0.f;
  if (MODE == 0) {
    #pragma unroll
    for (int k = 0; k < 8; k++) {
      size_t idx = (size_t)bimg*IMG + gy*WW + gx0 + k;
      float rv = accv[k] - rhs[idx];
      outQ[idx] = rv;
      outP[idx] = -rv;
      part += rv*rv;
    }
  } else {
    #pragma unroll
    for (int k = 0; k < 8; k++) {
      size_t idx = (size_t)bimg*IMG + gy*WW + gx0 + k;
      float pv = ssrc[sy+4][sx0+4+k];
      outQ[idx] = accv[k];
      part += pv * accv[k];
    }
  }
  atomic_block_sum(part, red, &acc[bimg]);
}

// ---------------- CG axpy update ---------------------------------------------------
__launch_bounds__(256)
__global__ void k_upd(float* __restrict__ xk, float* __restrict__ r,
                      const float* __restrict__ p, const float* __restrict__ q,
                      const float* __restrict__ num, const float* __restrict__ den,
                      float* __restrict__ rtrOut) {
  __shared__ float red[4];
  const int tid = threadIdx.x;
  const int bimg = blockIdx.x >> 8;
  const size_t idx4 = (size_t)blockIdx.x * 256 + tid;
  const float al = num[bimg] / den[bimg];
  float4 xv = ((const float4*)xk)[idx4];
  float4 pv = ((const float4*)p)[idx4];
  float4 rv = ((const float4*)r)[idx4];
  float4 qv = ((const float4*)q)[idx4];
  xv.x += al*pv.x; xv.y += al*pv.y; xv.z += al*pv.z; xv.w += al*pv.w;
  rv.x += al*qv.x; rv.y += al*qv.y; rv.z += al*qv.z; rv.w += al*qv.w;
  ((float4*)xk)[idx4] = xv;
  ((float4*)r)[idx4] = rv;
  float part = rv.x*rv.x + rv.y*rv.y + rv.z*rv.z + rv.w*rv.w;
  atomic_block_sum(part, red, &rtrOut[bimg]);
}

__launch_bounds__(256)
__global__ void k_final(const float* __restrict__ xk, const float* __restrict__ p,
                        const float* __restrict__ num, const float* __restrict__ den,
                        float* __restrict__ out) {
  const int tid = threadIdx.x;
  const int bimg = blockIdx.x >> 8;
  const size_t idx4 = (size_t)blockIdx.x * 256 + tid;
  const float al = num[bimg] / den[bimg];
  float4 xv = ((const float4*)xk)[idx4];
  float4 pv = ((const float4*)p)[idx4];
  float4 o;
  o.x = xv.x + al*pv.x; o.y = xv.y + al*pv.y; o.z = xv.z + al*pv.z; o.w = xv.w + al*pv.w;
  ((float4*)out)[idx4] = o;
}

extern "C" void kernel_launch(void* const* d_in, const int* in_sizes, int n_in,
                              void* d_out, int out_size, void* d_ws, size_t ws_size,
                              hipStream_t stream) {
  const float* sino = (const float*)d_in[0];
  const float* x    = (const float*)d_in[1];
  const float* laam = (const float*)d_in[2];
  const float* miu  = (const float*)d_in[3];
  const float* Kw   = (const float*)d_in[4];
  const float* Ka   = (const float*)d_in[5];
  const float* W1   = (const float*)d_in[6];
  const float* b1   = (const float*)d_in[7];
  const float* W2   = (const float*)d_in[8];
  const float* b2   = (const float*)d_in[9];
  const float* W3   = (const float*)d_in[10];
  const float* b3   = (const float*)d_in[11];

  float* ws = (float*)d_ws;
  float* xk = ws;
  float* r  = ws + (size_t)NTOT;
  float* p0 = ws + 2*(size_t)NTOT;
  float* p1 = ws + 3*(size_t)NTOT;
  float* q  = ws + 4*(size_t)NTOT;
  float* G  = ws + 5*(size_t)NTOT;
  float* accb = G + 128;
  float* den = accb;       // den[i*8 + b], i = 0..5
  float* rtr = accb + 48;  // rtr[j*8 + b], j = 0..5
  float* rhs = (float*)d_out;   // d_out doubles as rhs scratch until the end
  float* out = (float*)d_out;

  hipMemsetAsync(accb, 0, 96*sizeof(float), stream);
  k_prep<<<1, 128, 0, stream>>>(Ka, Kw, miu, G);
  k_cnn<<<dim3(32,32,8), 512, 0, stream>>>(x, W1,b1,W2,b2,W3,b3, xk);
  k_rhs<<<dim3(16,16,8), 256, 0, stream>>>(sino, x, laam, miu, Ka, Kw, rhs);

  dim3 mg(8,16,8);
  k_M<0><<<mg,256,0,stream>>>(xk, nullptr, rhs, r, p0, G, Ka, Kw, miu, nullptr, nullptr, &rtr[0]);
  // i = 0
  k_M<1><<<mg,256,0,stream>>>(p0, nullptr, nullptr, q, nullptr, G, Ka, Kw, miu, nullptr, nullptr, &den[0]);
  k_upd<<<2048,256,0,stream>>>(xk, r, p0, q, &rtr[0], &den[0], &rtr[8]);
  // i = 1..4
  float* pcur = p0; float* pnext = p1;
  for (int i = 1; i <= 4; i++) {
    k_M<2><<<mg,256,0,stream>>>(r, pcur, nullptr, q, pnext, G, Ka, Kw, miu, &rtr[8*i], &rtr[8*(i-1)], &den[8*i]);
    k_upd<<<2048,256,0,stream>>>(xk, r, pnext, q, &rtr[8*i], &den[8*i], &rtr[8*(i+1)]);
    float* t = pcur; pcur = pnext; pnext = t;
  }
  // final half step (i = 5)
  k_M<2><<<mg,256,0,stream>>>(r, pcur, nullptr, q, pnext, G, Ka, Kw, miu, &rtr[40], &rtr[32], &den[40]);
  k_final<<<2048,256,0,stream>>>(xk, pnext, &rtr[40], &den[40], out);
}

// Round 3
// 669.038 us; speedup vs baseline: 3.3699x; 3.3499x over previous
//
#include <hip/hip_runtime.h>

#define HH 512
#define WW 512
#define BB 8
#define IMG (HH*WW)
#define NTOT (BB*IMG)

typedef float f32x4 __attribute__((ext_vector_type(4)));
typedef short short8 __attribute__((ext_vector_type(8)));
typedef short short4s __attribute__((ext_vector_type(4)));

__device__ inline ushort f2bf(float f) {
  unsigned u = __float_as_uint(f);
  u += 0x7fffu + ((u >> 16) & 1u);
  return (ushort)(u >> 16);
}
__device__ inline float bf2f_lo(unsigned u) { return __uint_as_float((u & 0xffffu) << 16); }
__device__ inline float bf2f_hi(unsigned u) { return __uint_as_float(u & 0xffff0000u); }

__device__ inline void atomic_block_sum(float part, float* red, float* dst) {
  for (int off = 32; off > 0; off >>= 1) part += __shfl_down(part, off, 64);
  int lane = threadIdx.x & 63, w = threadIdx.x >> 6;
  if (lane == 0) red[w] = part;
  __syncthreads();
  if (threadIdx.x == 0) atomicAdd(dst, red[0] + red[1] + red[2] + red[3]);
}

// ---------------- fused CNN: xk = cnn(x) -------------------------------------------
__launch_bounds__(512)
__global__ void k_cnn(const float* __restrict__ x,
                      const float* __restrict__ W1, const float* __restrict__ b1,
                      const float* __restrict__ W2, const float* __restrict__ b2,
                      const float* __restrict__ W3, const float* __restrict__ b3,
                      float* __restrict__ xk) {
  __shared__ __align__(16) float  xs[22][23];
  __shared__ __align__(16) ushort h1s[22][712];   // 22 px * 32 ch + 8 pad (bf16)
  __shared__ __align__(16) ushort h2s[20][648];   // 20 px * 32 ch + 8 pad
  __shared__ __align__(16) ushort w2a[9216];      // A-frags: [(t*2+h)*64+l]*8+j
  __shared__ float w1s[288], b1s[32], b2s[32], w3s[288];

  const int tid = threadIdx.x;
  const int bimg = blockIdx.z;
  const int oy0 = blockIdx.y * 16, ox0 = blockIdx.x * 16;
  const float* xim = x + (size_t)bimg * IMG;

  for (int i = tid; i < 288; i += 512) { w1s[i] = W1[i]; w3s[i] = W3[i]; }
  if (tid < 32) { b1s[tid] = b1[tid]; b2s[tid] = b2[tid]; }
  for (int i = tid; i < 9216; i += 512) {
    int j = i & 7;
    int l = (i >> 3) & 63;
    int th = i >> 9;           // 0..17
    int t5 = th >> 1, hh = th & 1;
    int co = 16*hh + (l & 15);
    int ci = 8*(l >> 4) + j;
    w2a[i] = f2bf(W2[(co*32 + ci)*9 + t5]);
  }
  for (int i = tid; i < 484; i += 512) {
    int y = i / 22, xx = i % 22;
    int gy = oy0 + y - 3, gx = ox0 + xx - 3;
    float v = 0.f;
    if (gy >= 0 && gy < HH && gx >= 0 && gx < WW) v = xim[gy*WW + gx];
    xs[y][xx] = v;
  }
  __syncthreads();

  // conv1 -> h1 bf16. thread = (channel-pair cp, pixel-group pg): weights in regs.
  {
    const int cp = tid & 15;          // channel pair: ch 2cp, 2cp+1
    const int pg = tid >> 4;          // 0..31
    float wA[9], wB[9];
    #pragma unroll
    for (int k = 0; k < 9; k++) { wA[k] = w1s[(2*cp)*9 + k]; wB[k] = w1s[(2*cp+1)*9 + k]; }
    const float bA = b1s[2*cp], bB = b1s[2*cp+1];
    #pragma unroll 1
    for (int it = 0; it < 16; it++) {
      int px = pg + (it << 5);
      if (px < 484) {
        int y = px / 22, xx = px - 22*y;
        int gy = oy0 + y - 2, gx = ox0 + xx - 2;
        bool valid = (y < 20) && (xx < 20) && (gy >= 0) && (gy < HH) && (gx >= 0) && (gx < WW);
        unsigned pk = 0u;
        if (valid) {
          float a = bA, b_ = bB;
          #pragma unroll
          for (int ky = 0; ky < 3; ky++)
            #pragma unroll
            for (int kx = 0; kx < 3; kx++) {
              float xv = xs[y+ky][xx+kx];
              a  = fmaf(wA[ky*3+kx], xv, a);
              b_ = fmaf(wB[ky*3+kx], xv, b_);
            }
          a = fmaxf(a, 0.f); b_ = fmaxf(b_, 0.f);
          pk = (unsigned)f2bf(a) | ((unsigned)f2bf(b_) << 16);
        }
        *(unsigned*)&h1s[y][xx*32 + 2*cp] = pk;
      }
    }
  }
  __syncthreads();

  // conv2 via MFMA 16x16x32 bf16
  const int wv = tid >> 6, lane = tid & 63;
  const int nn = lane & 15, kg = lane >> 4;
  const int py = nn >> 2, px2 = nn & 3;
  for (int pb = wv; pb < 25; pb += 8) {
    const int pby = (pb / 5) * 4, pbx = (pb % 5) * 4;
    f32x4 accA = {0.f,0.f,0.f,0.f}, accB = {0.f,0.f,0.f,0.f};
    #pragma unroll
    for (int t5 = 0; t5 < 9; t5++) {
      const int ky = t5 / 3, kx = t5 % 3;
      const short8 bfr = *(const short8*)&h1s[pby + py + ky][(pbx + px2 + kx)*32 + kg*8];
      const short8 a0  = *(const short8*)&w2a[((t5*2+0)*64 + lane)*8];
      const short8 a1  = *(const short8*)&w2a[((t5*2+1)*64 + lane)*8];
      accA = __builtin_amdgcn_mfma_f32_16x16x32_bf16(a0, bfr, accA, 0, 0, 0);
      accB = __builtin_amdgcn_mfma_f32_16x16x32_bf16(a1, bfr, accB, 0, 0, 0);
    }
    const int h2y = pby + py, h2x = pbx + px2;
    const int gy = oy0 + h2y - 1, gx = ox0 + h2x - 1;
    const bool inb = (gy >= 0) && (gy < HH) && (gx >= 0) && (gx < WW);
    {
      int cb = 4*kg;
      short4s s;
      #pragma unroll
      for (int j = 0; j < 4; j++) {
        float v = inb ? fmaxf(accA[j] + b2s[cb+j], 0.f) : 0.f;
        s[j] = (short)f2bf(v);
      }
      *(short4s*)&h2s[h2y][h2x*32 + cb] = s;
      cb = 16 + 4*kg;
      #pragma unroll
      for (int j = 0; j < 4; j++) {
        float v = inb ? fmaxf(accB[j] + b2s[cb+j], 0.f) : 0.f;
        s[j] = (short)f2bf(v);
      }
      *(short4s*)&h2s[h2y][h2x*32 + cb] = s;
    }
  }
  __syncthreads();

  // conv3 + residual: all 512 threads, px = tid>>1, half = tid&1 (16 channels each)
  {
    const int px = tid >> 1, half = tid & 1;
    const int oy = px >> 4, ox = px & 15;
    float acc = 0.f;
    #pragma unroll
    for (int ky = 0; ky < 3; ky++)
      #pragma unroll
      for (int kx = 0; kx < 3; kx++) {
        const ushort* hp = &h2s[oy+ky][(ox+kx)*32 + 16*half];
        #pragma unroll
        for (int c8 = 0; c8 < 2; c8++) {
          uint4 u = *(const uint4*)(hp + c8*8);
          unsigned uu0 = u.x, uu1 = u.y, uu2 = u.z, uu3 = u.w;
          int ci = 16*half + c8*8;
          acc = fmaf(w3s[(ci+0)*9 + ky*3+kx], bf2f_lo(uu0), acc);
          acc = fmaf(w3s[(ci+1)*9 + ky*3+kx], bf2f_hi(uu0), acc);
          acc = fmaf(w3s[(ci+2)*9 + ky*3+kx], bf2f_lo(uu1), acc);
          acc = fmaf(w3s[(ci+3)*9 + ky*3+kx], bf2f_hi(uu1), acc);
          acc = fmaf(w3s[(ci+4)*9 + ky*3+kx], bf2f_lo(uu2), acc);
          acc = fmaf(w3s[(ci+5)*9 + ky*3+kx], bf2f_hi(uu2), acc);
          acc = fmaf(w3s[(ci+6)*9 + ky*3+kx], bf2f_lo(uu3), acc);
          acc = fmaf(w3s[(ci+7)*9 + ky*3+kx], bf2f_hi(uu3), acc);
        }
      }
    float other = __shfl_xor(acc, 1, 64);
    if (half == 0) {
      float total = acc + other + b3[0] + xs[oy+3][ox+3];
      xk[(size_t)bimg*IMG + (oy0+oy)*WW + (ox0+ox)] = total;
    }
  }
}

// ---------------- rhs = ATop(sino) + miu * WTop(softthresh(Wop(x))) ----------------
__launch_bounds__(256)
__global__ void k_rhs(const float* __restrict__ sino, const float* __restrict__ x,
                      const float* __restrict__ laam, const float* __restrict__ miu,
                      const float* __restrict__ Ka, const float* __restrict__ Kw,
                      float* __restrict__ rhs) {
  __shared__ float xs[36][37];
  __shared__ float ss[36][37];
  __shared__ float dz[4][34][35];
  __shared__ float kas[25], kws[36];
  int tid = threadIdx.x;
  int bimg = blockIdx.z;
  int oy0 = blockIdx.y*32, ox0 = blockIdx.x*32;
  const float* xim = x + (size_t)bimg*IMG;
  const float* sim = sino + (size_t)bimg*IMG;
  if (tid < 25) kas[tid] = Ka[tid];
  if (tid < 36) kws[tid] = Kw[tid];
  float lam = laam[0], mu = miu[0];
  for (int i = tid; i < 1296; i += 256) {
    int y = i/36, xx = i%36;
    int gy = oy0 + y - 2, gx = ox0 + xx - 2;
    bool in = (gy >= 0 && gy < HH && gx >= 0 && gx < WW);
    xs[y][xx] = in ? xim[gy*WW+gx] : 0.f;
    ss[y][xx] = in ? sim[gy*WW+gx] : 0.f;
  }
  __syncthreads();
  for (int i = tid; i < 1156; i += 256) {
    int dy = i/34, dx = i%34;
    int gy = oy0 + dy - 1, gx = ox0 + dx - 1;
    bool in = (gy >= 0 && gy < HH && gx >= 0 && gx < WW);
    #pragma unroll
    for (int ch = 0; ch < 4; ch++) {
      float v = 0.f;
      if (in) {
        float wu = 0.f;
        #pragma unroll
        for (int e = 0; e < 9; e++) wu = fmaf(kws[ch*9+e], xs[dy + e/3][dx + e%3], wu);
        v = fmaxf(wu - lam, 0.f) - fmaxf(-wu - lam, 0.f);
      }
      dz[ch][dy][dx] = v;
    }
  }
  __syncthreads();
  for (int i = tid; i < 1024; i += 256) {
    int oy = i/32, ox = i%32;
    float qa = 0.f;
    #pragma unroll
    for (int d = 0; d < 25; d++) qa = fmaf(kas[d], ss[oy + 4 - d/5][ox + 4 - d%5], qa);
    float wt = 0.f;
    #pragma unroll
    for (int ch = 0; ch < 4; ch++)
      #pragma unroll
      for (int d = 0; d < 9; d++)
        wt = fmaf(kws[ch*9+d], dz[ch][oy + 2 - d/3][ox + 2 - d%3], wt);
    rhs[(size_t)bimg*IMG + (oy0+oy)*WW + ox0+ox] = qa + mu*wt;
  }
}

// ---------------- M-apply: exact two-stage, uniform (no border special case) -------
// Tile 32 rows x 64 cols, 256 threads.
// MODE 0: src=xk, out r = M(xk)-rhs, p0 = -r, acc += <r,r>
// MODE 1: src=p,  out q = M(p),  acc += <p,q>
// MODE 2: p = -r + be*p_old (on the fly), write p_new, q=M(p), acc += <p,q>
template<int MODE>
__launch_bounds__(256)
__global__ void k_M(const float* __restrict__ srcA, const float* __restrict__ srcB,
                    const float* __restrict__ rhs,
                    float* __restrict__ outQ, float* __restrict__ outP,
                    const float* __restrict__ Ka, const float* __restrict__ Kw,
                    const float* __restrict__ miu,
                    const float* __restrict__ beN, const float* __restrict__ beD,
                    float* __restrict__ acc) {
  __shared__ __align__(16) float ssrc[40][76];   // p, halo 4, zero-padded; row = 304B (16B-mult)
  __shared__ __align__(16) float tbuf[36][68];   // Ap (36x68) then per-ch Wp (34x66); row 272B
  __shared__ float red[4];
  const int tid = threadIdx.x;
  const int bimg = blockIdx.z;
  const int oy0 = blockIdx.y*32, ox0 = blockIdx.x*64;
  const float mu = miu[0];
  float be = 0.f;
  if (MODE == 2) be = beN[bimg] / beD[bimg];
  const float* sA = srcA + (size_t)bimg*IMG;
  const float* sB = (MODE == 2) ? srcB + (size_t)bimg*IMG : nullptr;

  // ---- stage p (zero outside image and in pad cols 72..75) ----
  for (int i = tid; i < 40*76; i += 256) {
    int ly = i/76, lx = i%76;
    int gy = oy0 + ly - 4, gx = ox0 + lx - 4;
    bool in = (lx < 72) && (gy >= 0 && gy < HH && gx >= 0 && gx < WW);
    float v = 0.f;
    if (MODE == 2) {
      if (in) {
        v = -sA[gy*WW+gx] + be * sB[gy*WW+gx];
        if (ly >= 4 && ly < 36 && lx >= 4 && lx < 68)
          outP[(size_t)bimg*IMG + gy*WW + gx] = v;
      }
    } else {
      if (in) v = sA[gy*WW+gx];
    }
    ssrc[ly][lx] = v;
  }
  __syncthreads();

  // ---- stage 1A: tbuf = Ap on halo-2 grid (36 x 68), zero outside image ----
  {
    float ka[25];
    #pragma unroll
    for (int k = 0; k < 25; k++) ka[k] = Ka[k];
    #pragma unroll 1
    for (int item = tid; item < 324; item += 256) {     // 36 rows x 9 chunks of 8
      int iy = item / 9, c = item - 9*iy;
      int x0 = c*8;
      float t[8];
      #pragma unroll
      for (int j = 0; j < 8; j++) t[j] = 0.f;
      #pragma unroll
      for (int dy = 0; dy < 5; dy++) {
        const float* row = &ssrc[iy+dy][x0];
        float4 r0 = *(const float4*)(row);
        float4 r1 = *(const float4*)(row+4);
        float4 r2 = *(const float4*)(row+8);
        float w[12] = {r0.x,r0.y,r0.z,r0.w, r1.x,r1.y,r1.z,r1.w, r2.x,r2.y,r2.z,r2.w};
        #pragma unroll
        for (int j = 0; j < 8; j++)
          #pragma unroll
          for (int dx = 0; dx < 5; dx++)
            t[j] = fmaf(ka[dy*5+dx], w[j+dx], t[j]);
      }
      int gy = oy0 + iy - 2;
      bool rin = (gy >= 0 && gy < HH);
      #pragma unroll
      for (int j = 0; j < 8; j++) {
        int ix = x0 + j;
        if (ix < 68) {
          int gx = ox0 + ix - 2;
          tbuf[iy][ix] = (rin && gx >= 0 && gx < WW) ? t[j] : 0.f;
        }
      }
    }
  }
  __syncthreads();

  // ---- stage 2A: qa = correlate Ka over tbuf ----
  const int sy = tid >> 3, sx0 = (tid & 7) * 8;
  float accv[8];
  #pragma unroll
  for (int k = 0; k < 8; k++) accv[k] = 0.f;
  {
    float ka[25];
    #pragma unroll
    for (int k = 0; k < 25; k++) ka[k] = Ka[k];
    #pragma unroll
    for (int dy = 0; dy < 5; dy++) {
      const float* row = &tbuf[sy+4-dy][sx0];
      float4 r0 = *(const float4*)(row);
      float4 r1 = *(const float4*)(row+4);
      float4 r2 = *(const float4*)(row+8);
      float w[12] = {r0.x,r0.y,r0.z,r0.w, r1.x,r1.y,r1.z,r1.w, r2.x,r2.y,r2.z,r2.w};
      #pragma unroll
      for (int k = 0; k < 8; k++)
        #pragma unroll
        for (int dx = 0; dx < 5; dx++)
          accv[k] = fmaf(ka[dy*5+dx], w[k+4-dx], accv[k]);
    }
  }
  __syncthreads();

  // ---- per channel: tbuf = Wp_ch (34 x 66), then accumulate mu * correlation ----
  #pragma unroll 1
  for (int ch = 0; ch < 4; ch++) {
    {
      float kw[9];
      #pragma unroll
      for (int k = 0; k < 9; k++) kw[k] = Kw[ch*9 + k];
      #pragma unroll 1
      for (int item = tid; item < 306; item += 256) {   // 34 rows x 9 chunks of 8
        int iy = item / 9, c = item - 9*iy;
        int x0 = c*8;
        float t[8];
        #pragma unroll
        for (int j = 0; j < 8; j++) t[j] = 0.f;
        #pragma unroll
        for (int dy = 0; dy < 3; dy++) {
          const float* row = &ssrc[iy+dy+2][x0];
          float4 r0 = *(const float4*)(row);
          float4 r1 = *(const float4*)(row+4);
          float4 r2 = *(const float4*)(row+8);
          float w[12] = {r0.x,r0.y,r0.z,r0.w, r1.x,r1.y,r1.z,r1.w, r2.x,r2.y,r2.z,r2.w};
          #pragma unroll
          for (int j = 0; j < 8; j++)
            #pragma unroll
            for (int dx = 0; dx < 3; dx++)
              t[j] = fmaf(kw[dy*3+dx], w[j+dx+2], t[j]);
        }
        int gy = oy0 + iy - 1;
        bool rin = (gy >= 0 && gy < HH);
        #pragma unroll
        for (int j = 0; j < 8; j++) {
          int ix = x0 + j;
          if (ix < 66) {
            int gx = ox0 + ix - 1;
            tbuf[iy][ix] = (rin && gx >= 0 && gx < WW) ? t[j] : 0.f;
          }
        }
      }
    }
    __syncthreads();
    {
      float kw[9];
      #pragma unroll
      for (int k = 0; k < 9; k++) kw[k] = mu * Kw[ch*9 + k];
      #pragma unroll
      for (int dy = 0; dy < 3; dy++) {
        const float* row = &tbuf[sy+2-dy][sx0];
        float4 r0 = *(const float4*)(row);
        float4 r1 = *(const float4*)(row+4);
        float4 r2 = *(const float4*)(row+8);
        float w[12] = {r0.x,r0.y,r0.z,r0.w, r1.x,r1.y,r1.z,r1.w, r2.x,r2.y,r2.z,r2.w};
        #pragma unroll
        for (int k = 0; k < 8; k++)
          #pragma unroll
          for (int dx = 0; dx < 3; dx++)
            accv[k] = fmaf(kw[dy*3+dx], w[k+2-dx], accv[k]);
      }
    }
    __syncthreads();
  }

  // ---- epilogue ----
  const int gy = oy0 + sy, gx0 = ox0 + sx0;
  float part = 0.f;
  if (MODE == 0) {
    #pragma unroll
    for (int k = 0; k < 8; k++) {
      size_t idx = (size_t)bimg*IMG + gy*WW + gx0 + k;
      float rv = accv[k] - rhs[idx];
      outQ[idx] = rv;
      outP[idx] = -rv;
      part += rv*rv;
    }
  } else {
    #pragma unroll
    for (int k = 0; k < 8; k++) {
      size_t idx = (size_t)bimg*IMG + gy*WW + gx0 + k;
      float pv = ssrc[sy+4][sx0+4+k];
      outQ[idx] = accv[k];
      part += pv * accv[k];
    }
  }
  atomic_block_sum(part, red, &acc[bimg]);
}

// ---------------- CG axpy update ---------------------------------------------------
__launch_bounds__(256)
__global__ void k_upd(float* __restrict__ xk, float* __restrict__ r,
                      const float* __restrict__ p, const float* __restrict__ q,
                      const float* __restrict__ num, const float* __restrict__ den,
                      float* __restrict__ rtrOut) {
  __shared__ float red[4];
  const int tid = threadIdx.x;
  const int bimg = blockIdx.x >> 8;
  const size_t idx4 = (size_t)blockIdx.x * 256 + tid;
  const float al = num[bimg] / den[bimg];
  float4 xv = ((const float4*)xk)[idx4];
  float4 pv = ((const float4*)p)[idx4];
  float4 rv = ((const float4*)r)[idx4];
  float4 qv = ((const float4*)q)[idx4];
  xv.x += al*pv.x; xv.y += al*pv.y; xv.z += al*pv.z; xv.w += al*pv.w;
  rv.x += al*qv.x; rv.y += al*qv.y; rv.z += al*qv.z; rv.w += al*qv.w;
  ((float4*)xk)[idx4] = xv;
  ((float4*)r)[idx4] = rv;
  float part = rv.x*rv.x + rv.y*rv.y + rv.z*rv.z + rv.w*rv.w;
  atomic_block_sum(part, red, &rtrOut[bimg]);
}

__launch_bounds__(256)
__global__ void k_final(const float* __restrict__ xk, const float* __restrict__ p,
                        const float* __restrict__ num, const float* __restrict__ den,
                        float* __restrict__ out) {
  const int tid = threadIdx.x;
  const int bimg = blockIdx.x >> 8;
  const size_t idx4 = (size_t)blockIdx.x * 256 + tid;
  const float al = num[bimg] / den[bimg];
  float4 xv = ((const float4*)xk)[idx4];
  float4 pv = ((const float4*)p)[idx4];
  float4 o;
  o.x = xv.x + al*pv.x; o.y = xv.y + al*pv.y; o.z = xv.z + al*pv.z; o.w = xv.w + al*pv.w;
  ((float4*)out)[idx4] = o;
}

extern "C" void kernel_launch(void* const* d_in, const int* in_sizes, int n_in,
                              void* d_out, int out_size, void* d_ws, size_t ws_size,
                              hipStream_t stream) {
  const float* sino = (const float*)d_in[0];
  const float* x    = (const float*)d_in[1];
  const float* laam = (const float*)d_in[2];
  const float* miu  = (const float*)d_in[3];
  const float* Kw   = (const float*)d_in[4];
  const float* Ka   = (const float*)d_in[5];
  const float* W1   = (const float*)d_in[6];
  const float* b1   = (const float*)d_in[7];
  const float* W2   = (const float*)d_in[8];
  const float* b2   = (const float*)d_in[9];
  const float* W3   = (const float*)d_in[10];
  const float* b3   = (const float*)d_in[11];

  float* ws = (float*)d_ws;
  float* xk = ws;
  float* r  = ws + (size_t)NTOT;
  float* p0 = ws + 2*(size_t)NTOT;
  float* p1 = ws + 3*(size_t)NTOT;
  float* q  = ws + 4*(size_t)NTOT;
  float* accb = ws + 5*(size_t)NTOT;
  float* den = accb;       // den[i*8 + b], i = 0..5
  float* rtr = accb + 48;  // rtr[j*8 + b], j = 0..5
  float* rhs = (float*)d_out;   // d_out doubles as rhs scratch until the end
  float* out = (float*)d_out;

  hipMemsetAsync(accb, 0, 96*sizeof(float), stream);
  k_cnn<<<dim3(32,32,8), 512, 0, stream>>>(x, W1,b1,W2,b2,W3,b3, xk);
  k_rhs<<<dim3(16,16,8), 256, 0, stream>>>(sino, x, laam, miu, Ka, Kw, rhs);

  dim3 mg(8,16,8);
  k_M<0><<<mg,256,0,stream>>>(xk, nullptr, rhs, r, p0, Ka, Kw, miu, nullptr, nullptr, &rtr[0]);
  // i = 0
  k_M<1><<<mg,256,0,stream>>>(p0, nullptr, nullptr, q, nullptr, Ka, Kw, miu, nullptr, nullptr, &den[0]);
  k_upd<<<2048,256,0,stream>>>(xk, r, p0, q, &rtr[0], &den[0], &rtr[8]);
  // i = 1..4
  float* pcur = p0; float* pnext = p1;
  for (int i = 1; i <= 4; i++) {
    k_M<2><<<mg,256,0,stream>>>(r, pcur, nullptr, q, pnext, Ka, Kw, miu, &rtr[8*i], &rtr[8*(i-1)], &den[8*i]);
    k_upd<<<2048,256,0,stream>>>(xk, r, pnext, q, &rtr[8*i], &den[8*i], &rtr[8*(i+1)]);
    float* t = pcur; pcur = pnext; pnext = t;
  }
  // final half step (i = 5)
  k_M<2><<<mg,256,0,stream>>>(r, pcur, nullptr, q, pnext, Ka, Kw, miu, &rtr[40], &rtr[32], &den[40]);
  k_final<<<2048,256,0,stream>>>(xk, pnext, &rtr[40], &den[40], out);
}

// Round 5
// 587.556 us; speedup vs baseline: 3.8372x; 1.1387x over previous
//
#include <hip/hip_runtime.h>

#define HH 512
#define WW 512
#define BB 8
#define IMG (HH*WW)
#define NTOT (BB*IMG)

typedef float f32x4 __attribute__((ext_vector_type(4)));
typedef _Float16 half8 __attribute__((ext_vector_type(8)));

__device__ inline uint f2h2(float a, float b) {
  uint d; asm("v_cvt_pkrtz_f16_f32 %0, %1, %2" : "=v"(d) : "v"(a), "v"(b)); return d;
}
__device__ inline uint pkfma(uint a, uint b, uint c) {
  uint d; asm("v_pk_fma_f16 %0, %1, %2, %3" : "=v"(d) : "v"(a), "v"(b), "v"(c)); return d;
}
__device__ inline uint pkmax0(uint a) {
  uint d, z = 0u; asm("v_pk_max_f16 %0, %1, %2" : "=v"(d) : "v"(a), "v"(z)); return d;
}

__device__ inline void atomic_block_sum(float part, float* red, float* dst) {
  for (int off = 32; off > 0; off >>= 1) part += __shfl_down(part, off, 64);
  int lane = threadIdx.x & 63, w = threadIdx.x >> 6;
  if (lane == 0) red[w] = part;
  __syncthreads();
  if (threadIdx.x == 0) atomicAdd(dst, red[0] + red[1] + red[2] + red[3]);
}

// ---------------- prep: G stencil + fp16 weight packing ----------------------------
__global__ void k_prep(const float* __restrict__ Ka, const float* __restrict__ Kw,
                       const float* __restrict__ miu,
                       const float* __restrict__ W1, const float* __restrict__ b1,
                       const float* __restrict__ W2, const float* __restrict__ W3,
                       float* __restrict__ G, ushort* __restrict__ w2pk,
                       uint* __restrict__ w1pk, uint* __restrict__ b1pk,
                       ushort* __restrict__ w3fr) {
  int tid = threadIdx.x;
  if (tid < 81) {
    int oy = tid / 9 - 4, ox = tid % 9 - 4;
    float mu = miu[0];
    float ga = 0.f;
    for (int dy = 0; dy < 5; dy++)
      for (int dx = 0; dx < 5; dx++) {
        int ey = dy + oy, ex = dx + ox;
        if (ey >= 0 && ey < 5 && ex >= 0 && ex < 5) ga += Ka[dy*5+dx] * Ka[ey*5+ex];
      }
    float gw = 0.f;
    if (oy >= -2 && oy <= 2 && ox >= -2 && ox <= 2) {
      for (int ch = 0; ch < 4; ch++)
        for (int dy = 0; dy < 3; dy++)
          for (int dx = 0; dx < 3; dx++) {
            int ey = dy + oy, ex = dx + ox;
            if (ey >= 0 && ey < 3 && ex >= 0 && ex < 3)
              gw += Kw[ch*9 + dy*3+dx] * Kw[ch*9 + ey*3+ex];
          }
    }
    G[tid] = ga + mu * gw;
  }
  // W2 A-frags: [(t5*2+h)*64 + lane]*8 + j ; co = 16h+(l&15), ci = 8(l>>4)+j
  for (int i = tid; i < 9216; i += 256) {
    int j = i & 7, l = (i >> 3) & 63, f = i >> 9;
    int t5 = f >> 1, h = f & 1;
    int co = 16*h + (l & 15), ci = 8*(l >> 4) + j;
    w2pk[i] = (ushort)(f2h2(W2[(co*32 + ci)*9 + t5], 0.f) & 0xffffu);
  }
  // W1 half2 pairs: [cp*9 + tap] = (ch 2cp, 2cp+1)
  if (tid < 144) {
    int cp = tid / 9, t = tid % 9;
    w1pk[tid] = f2h2(W1[(2*cp)*9 + t], W1[(2*cp+1)*9 + t]);
  }
  if (tid < 16) b1pk[tid] = f2h2(b1[2*tid], b1[2*tid+1]);
  // W3 B-frag: lane l: col=tap=l&15 (tap<9 else 0), k=ch=8(l>>4)+j
  for (int i = tid; i < 512; i += 256) {
    int j = i & 7, l = i >> 3;
    int tap = l & 15, ch = 8*(l >> 4) + j;
    w3fr[i] = (tap < 9) ? (ushort)(f2h2(W3[ch*9 + tap], 0.f) & 0xffffu) : (ushort)0;
  }
}

// ---------------- fused CNN: xk = cnn(x), fp16/MFMA --------------------------------
// tile 16x16 out; h1: 20x20 px; h2: 18x18 px; all channel data fp16.
__launch_bounds__(512)
__global__ void k_cnn(const float* __restrict__ x,
                      const ushort* __restrict__ w2pk, const uint* __restrict__ w1pk,
                      const uint* __restrict__ b1pk, const ushort* __restrict__ w3fr,
                      const float* __restrict__ b2, const float* __restrict__ b3,
                      float* __restrict__ xk) {
  __shared__ __align__(16) uint  xs_h2[528];        // 22 rows x 24 cols, half2-bcast
  __shared__ __align__(16) uint  h1u[20*328];       // [row][kg*80 + px*4 + c&3]
  __shared__ __align__(16) uint  h2u[18*296];       // [row][slice*72 + px*4 + ...]
  __shared__ __align__(16) float Tlds[18*180];      // [ty][tap*20 + tx]

  const int tid = threadIdx.x;
  const int bimg = blockIdx.z;
  const int oy0 = blockIdx.y * 16, ox0 = blockIdx.x * 16;
  const float* xim = x + (size_t)bimg * IMG;

  // ---- stage x as half2-broadcast (rows oy0-3..+18, cols ox0-4..+19) ----
  for (int i = tid; i < 528; i += 512) {
    int ly = i / 24, lx = i % 24;
    int gy = oy0 + ly - 3, gx = ox0 + lx - 4;
    float v = 0.f;
    if ((unsigned)gy < HH && (unsigned)gx < WW) v = xim[gy*WW + gx];
    xs_h2[i] = f2h2(v, v);
  }
  __syncthreads();

  // ---- conv1: thread = (chpair cp, strip-group sg); 20 rows x 5 strips of 4 px ----
  {
    const int cp = tid & 15;
    const int sg = tid >> 4;
    uint w1r[9];
    #pragma unroll
    for (int k = 0; k < 9; k++) w1r[k] = w1pk[cp*9 + k];
    const uint b1v = b1pk[cp];
    const int kg = cp >> 2, cl = cp & 3;
    #pragma unroll 1
    for (int s = sg; s < 100; s += 32) {
      int row = s / 5, st = s - 5*row;
      int px0 = st * 4;
      uint acc0 = b1v, acc1 = b1v, acc2 = b1v, acc3 = b1v;
      #pragma unroll
      for (int ky = 0; ky < 3; ky++) {
        int base = (row + ky) * 24 + px0;
        uint4 xa = *(const uint4*)&xs_h2[base];
        uint4 xb = *(const uint4*)&xs_h2[base + 4];
        uint xu[8] = {xa.x, xa.y, xa.z, xa.w, xb.x, xb.y, xb.z, xb.w};
        #pragma unroll
        for (int kx = 0; kx < 3; kx++) {
          uint w = w1r[ky*3 + kx];
          acc0 = pkfma(w, xu[1 + kx], acc0);
          acc1 = pkfma(w, xu[2 + kx], acc1);
          acc2 = pkfma(w, xu[3 + kx], acc2);
          acc3 = pkfma(w, xu[4 + kx], acc3);
        }
      }
      int Y = oy0 + row - 2;
      bool rin = (unsigned)Y < HH;
      int ob = row*328 + kg*80 + px0*4 + cl;
      #pragma unroll
      for (int i = 0; i < 4; i++) {
        int X = ox0 + px0 + i - 2;
        uint v = (rin && (unsigned)X < WW) ?
                 pkmax0(i == 0 ? acc0 : (i == 1 ? acc1 : (i == 2 ? acc2 : acc3))) : 0u;
        h1u[ob + i*4] = v;
      }
    }
  }
  __syncthreads();

  // ---- conv2 via MFMA f16 16x16x32: 27 tasks (9 row-pairs x 3 col strips) ----
  const int wv = tid >> 6, lane = tid & 63;
  const int nn = lane & 15, kg = lane >> 4;
  {
    half8 afr[9][2];
    #pragma unroll
    for (int t5 = 0; t5 < 9; t5++) {
      afr[t5][0] = ((const half8*)w2pk)[(t5*2 + 0)*64 + lane];
      afr[t5][1] = ((const half8*)w2pk)[(t5*2 + 1)*64 + lane];
    }
    float b2A[4], b2B[4];
    #pragma unroll
    for (int j = 0; j < 4; j++) { b2A[j] = b2[4*kg + j]; b2B[j] = b2[16 + 4*kg + j]; }

    #pragma unroll 1
    for (int t = wv; t < 27; t += 8) {
      int rp = t / 3, cs = t - 3*rp;
      int tx0 = (cs == 2) ? 10 : (cs << 3);
      int brow = 2*rp + (nn >> 3);
      int bcol = tx0 + (nn & 7);
      f32x4 accA = {0.f,0.f,0.f,0.f}, accB = {0.f,0.f,0.f,0.f};
      #pragma unroll
      for (int ky = 0; ky < 3; ky++)
        #pragma unroll
        for (int kx = 0; kx < 3; kx++) {
          const half8 bfr = *(const half8*)&h1u[(brow+ky)*328 + kg*80 + (bcol+kx)*4];
          accA = __builtin_amdgcn_mfma_f32_16x16x32_f16(afr[ky*3+kx][0], bfr, accA, 0, 0, 0);
          accB = __builtin_amdgcn_mfma_f32_16x16x32_f16(afr[ky*3+kx][1], bfr, accB, 0, 0, 0);
        }
      int gy = oy0 + brow - 1, gx = ox0 + bcol - 1;
      bool inb = ((unsigned)gy < HH) && ((unsigned)gx < WW);
      float v0 = inb ? fmaxf(accA[0] + b2A[0], 0.f) : 0.f;
      float v1 = inb ? fmaxf(accA[1] + b2A[1], 0.f) : 0.f;
      float v2 = inb ? fmaxf(accA[2] + b2A[2], 0.f) : 0.f;
      float v3 = inb ? fmaxf(accA[3] + b2A[3], 0.f) : 0.f;
      uint2 uA = make_uint2(f2h2(v0, v1), f2h2(v2, v3));
      v0 = inb ? fmaxf(accB[0] + b2B[0], 0.f) : 0.f;
      v1 = inb ? fmaxf(accB[1] + b2B[1], 0.f) : 0.f;
      v2 = inb ? fmaxf(accB[2] + b2B[2], 0.f) : 0.f;
      v3 = inb ? fmaxf(accB[3] + b2B[3], 0.f) : 0.f;
      uint2 uB = make_uint2(f2h2(v0, v1), f2h2(v2, v3));
      int base = brow*296 + bcol*4 + (kg & 1)*2;
      *(uint2*)&h2u[base + (kg >> 1)*72]       = uA;   // ch 4kg..4kg+3
      *(uint2*)&h2u[base + (2 + (kg >> 1))*72] = uB;   // ch 16+4kg..
    }
  }
  __syncthreads();

  // ---- conv3 stage 1 via MFMA: T(px, tap) = <h2(px,:), w3(:,tap)> ----
  {
    const half8 w3f = ((const half8*)w3fr)[lane];
    const int tap = nn;
    #pragma unroll 1
    for (int t = wv; t < 27; t += 8) {
      int rp = t / 3, cs = t - 3*rp;
      int tx0 = (cs == 2) ? 10 : (cs << 3);
      int ay = 2*rp + (nn >> 3);
      int ax = tx0 + (nn & 7);
      const half8 afrag = *(const half8*)&h2u[ay*296 + kg*72 + ax*4];
      f32x4 z = {0.f,0.f,0.f,0.f};
      f32x4 T4 = __builtin_amdgcn_mfma_f32_16x16x32_f16(afrag, w3f, z, 0, 0, 0);
      if (tap < 9) {
        int ty = 2*rp + (kg >> 1);
        int txb = tx0 + 4*(kg & 1);
        float* dst = &Tlds[ty*180 + tap*20 + txb];
        if (cs == 2) {
          dst[0] = T4[0]; dst[1] = T4[1]; dst[2] = T4[2]; dst[3] = T4[3];
        } else {
          *(f32x4*)dst = T4;
        }
      }
    }
  }
  __syncthreads();

  // ---- conv3 gather + residual ----
  if (tid < 256) {
    int oy = tid >> 4, ox = tid & 15;
    float s = b3[0] + xim[(size_t)(oy0+oy)*WW + ox0 + ox];
    #pragma unroll
    for (int ky = 0; ky < 3; ky++)
      #pragma unroll
      for (int kx = 0; kx < 3; kx++)
        s += Tlds[(oy+ky)*180 + (3*ky+kx)*20 + (ox+kx)];
    xk[(size_t)bimg*IMG + (size_t)(oy0+oy)*WW + ox0 + ox] = s;
  }
}

// ---------------- rhs = ATop(sino) + miu * WTop(softthresh(Wop(x))) ----------------
__launch_bounds__(256)
__global__ void k_rhs(const float* __restrict__ sino, const float* __restrict__ x,
                      const float* __restrict__ laam, const float* __restrict__ miu,
                      const float* __restrict__ Ka, const float* __restrict__ Kw,
                      float* __restrict__ rhs) {
  __shared__ float xs[36][37];
  __shared__ float ss[36][37];
  __shared__ float dz[4][34][35];
  __shared__ float kas[25], kws[36];
  int tid = threadIdx.x;
  int bimg = blockIdx.z;
  int oy0 = blockIdx.y*32, ox0 = blockIdx.x*32;
  const float* xim = x + (size_t)bimg*IMG;
  const float* sim = sino + (size_t)bimg*IMG;
  if (tid < 25) kas[tid] = Ka[tid];
  if (tid < 36) kws[tid] = Kw[tid];
  float lam = laam[0], mu = miu[0];
  for (int i = tid; i < 1296; i += 256) {
    int y = i/36, xx = i%36;
    int gy = oy0 + y - 2, gx = ox0 + xx - 2;
    bool in = (gy >= 0 && gy < HH && gx >= 0 && gx < WW);
    xs[y][xx] = in ? xim[gy*WW+gx] : 0.f;
    ss[y][xx] = in ? sim[gy*WW+gx] : 0.f;
  }
  __syncthreads();
  for (int i = tid; i < 1156; i += 256) {
    int dy = i/34, dx = i%34;
    int gy = oy0 + dy - 1, gx = ox0 + dx - 1;
    bool in = (gy >= 0 && gy < HH && gx >= 0 && gx < WW);
    #pragma unroll
    for (int ch = 0; ch < 4; ch++) {
      float v = 0.f;
      if (in) {
        float wu = 0.f;
        #pragma unroll
        for (int e = 0; e < 9; e++) wu = fmaf(kws[ch*9+e], xs[dy + e/3][dx + e%3], wu);
        v = fmaxf(wu - lam, 0.f) - fmaxf(-wu - lam, 0.f);
      }
      dz[ch][dy][dx] = v;
    }
  }
  __syncthreads();
  for (int i = tid; i < 1024; i += 256) {
    int oy = i/32, ox = i%32;
    float qa = 0.f;
    #pragma unroll
    for (int d = 0; d < 25; d++) qa = fmaf(kas[d], ss[oy + 4 - d/5][ox + 4 - d%5], qa);
    float wt = 0.f;
    #pragma unroll
    for (int ch = 0; ch < 4; ch++)
      #pragma unroll
      for (int d = 0; d < 9; d++)
        wt = fmaf(kws[ch*9+d], dz[ch][oy + 2 - d/3][ox + 2 - d%3], wt);
    rhs[(size_t)bimg*IMG + (oy0+oy)*WW + ox0+ox] = qa + mu*wt;
  }
}

// ---------------- M-apply: interior = 9x9 G-stencil, edge = exact two-stage --------
template<int MODE>
__launch_bounds__(256)
__global__ void k_M(const float* __restrict__ srcA, const float* __restrict__ srcB,
                    const float* __restrict__ rhs,
                    float* __restrict__ outQ, float* __restrict__ outP,
                    const float* __restrict__ G,
                    const float* __restrict__ Ka, const float* __restrict__ Kw,
                    const float* __restrict__ miu,
                    const float* __restrict__ beN, const float* __restrict__ beD,
                    float* __restrict__ acc) {
  __shared__ __align__(16) float ssrc[40][76];
  __shared__ __align__(16) float tbuf[36][68];
  __shared__ float Gs[81];
  __shared__ float red[4];
  const int tid = threadIdx.x;
  const int bimg = blockIdx.z;
  const int oy0 = blockIdx.y*32, ox0 = blockIdx.x*64;
  const bool edgeB = (blockIdx.y == 0) || (blockIdx.y == gridDim.y-1) ||
                     (blockIdx.x == 0) || (blockIdx.x == gridDim.x-1);
  if (tid < 81) Gs[tid] = G[tid];
  const float mu = miu[0];
  float be = 0.f;
  if (MODE == 2) be = beN[bimg] / beD[bimg];
  const float* sA = srcA + (size_t)bimg*IMG;
  const float* sB = (MODE == 2) ? srcB + (size_t)bimg*IMG : nullptr;

  for (int i = tid; i < 40*76; i += 256) {
    int ly = i/76, lx = i%76;
    int gy = oy0 + ly - 4, gx = ox0 + lx - 4;
    bool in = (lx < 72) && (gy >= 0 && gy < HH && gx >= 0 && gx < WW);
    float v = 0.f;
    if (MODE == 2) {
      if (in) {
        v = -sA[gy*WW+gx] + be * sB[gy*WW+gx];
        if (ly >= 4 && ly < 36 && lx >= 4 && lx < 68)
          outP[(size_t)bimg*IMG + gy*WW + gx] = v;
      }
    } else {
      if (in) v = sA[gy*WW+gx];
    }
    ssrc[ly][lx] = v;
  }
  __syncthreads();

  const int sy = tid >> 3, sx0 = (tid & 7) * 8;
  float accv[8];
  #pragma unroll
  for (int k = 0; k < 8; k++) accv[k] = 0.f;

  if (!edgeB) {
    // interior: exact via composed 9x9 stencil
    #pragma unroll 1
    for (int oyy = 0; oyy < 9; oyy++) {
      float g[9];
      #pragma unroll
      for (int t = 0; t < 9; t++) g[t] = Gs[oyy*9+t];
      const float* row = &ssrc[sy+oyy][sx0];
      float4 r0 = *(const float4*)(row);
      float4 r1 = *(const float4*)(row+4);
      float4 r2 = *(const float4*)(row+8);
      float4 r3 = *(const float4*)(row+12);
      float v[16] = {r0.x,r0.y,r0.z,r0.w, r1.x,r1.y,r1.z,r1.w,
                     r2.x,r2.y,r2.z,r2.w, r3.x,r3.y,r3.z,r3.w};
      #pragma unroll
      for (int k = 0; k < 8; k++) {
        float a = accv[k];
        #pragma unroll
        for (int t = 0; t < 9; t++) a = fmaf(g[t], v[k+t], a);
        accv[k] = a;
      }
    }
  } else {
    // edge: exact two-stage with intermediate SAME-crop
    {
      float ka[25];
      #pragma unroll
      for (int k = 0; k < 25; k++) ka[k] = Ka[k];
      #pragma unroll 1
      for (int item = tid; item < 324; item += 256) {
        int iy = item / 9, c = item - 9*iy;
        int x0 = c*8;
        float t[8];
        #pragma unroll
        for (int j = 0; j < 8; j++) t[j] = 0.f;
        #pragma unroll
        for (int dy = 0; dy < 5; dy++) {
          const float* row = &ssrc[iy+dy][x0];
          float4 r0 = *(const float4*)(row);
          float4 r1 = *(const float4*)(row+4);
          float4 r2 = *(const float4*)(row+8);
          float w[12] = {r0.x,r0.y,r0.z,r0.w, r1.x,r1.y,r1.z,r1.w, r2.x,r2.y,r2.z,r2.w};
          #pragma unroll
          for (int j = 0; j < 8; j++)
            #pragma unroll
            for (int dx = 0; dx < 5; dx++)
              t[j] = fmaf(ka[dy*5+dx], w[j+dx], t[j]);
        }
        int gy = oy0 + iy - 2;
        bool rin = (gy >= 0 && gy < HH);
        #pragma unroll
        for (int j = 0; j < 8; j++) {
          int ix = x0 + j;
          if (ix < 68) {
            int gx = ox0 + ix - 2;
            tbuf[iy][ix] = (rin && gx >= 0 && gx < WW) ? t[j] : 0.f;
          }
        }
      }
    }
    __syncthreads();
    {
      float ka[25];
      #pragma unroll
      for (int k = 0; k < 25; k++) ka[k] = Ka[k];
      #pragma unroll
      for (int dy = 0; dy < 5; dy++) {
        const float* row = &tbuf[sy+4-dy][sx0];
        float4 r0 = *(const float4*)(row);
        float4 r1 = *(const float4*)(row+4);
        float4 r2 = *(const float4*)(row+8);
        float w[12] = {r0.x,r0.y,r0.z,r0.w, r1.x,r1.y,r1.z,r1.w, r2.x,r2.y,r2.z,r2.w};
        #pragma unroll
        for (int k = 0; k < 8; k++)
          #pragma unroll
          for (int dx = 0; dx < 5; dx++)
            accv[k] = fmaf(ka[dy*5+dx], w[k+4-dx], accv[k]);
      }
    }
    __syncthreads();
    #pragma unroll 1
    for (int ch = 0; ch < 4; ch++) {
      {
        float kw[9];
        #pragma unroll
        for (int k = 0; k < 9; k++) kw[k] = Kw[ch*9 + k];
        #pragma unroll 1
        for (int item = tid; item < 306; item += 256) {
          int iy = item / 9, c = item - 9*iy;
          int x0 = c*8;
          float t[8];
          #pragma unroll
          for (int j = 0; j < 8; j++) t[j] = 0.f;
          #pragma unroll
          for (int dy = 0; dy < 3; dy++) {
            const float* row = &ssrc[iy+dy+2][x0];
            float4 r0 = *(const float4*)(row);
            float4 r1 = *(const float4*)(row+4);
            float4 r2 = *(const float4*)(row+8);
            float w[12] = {r0.x,r0.y,r0.z,r0.w, r1.x,r1.y,r1.z,r1.w, r2.x,r2.y,r2.z,r2.w};
            #pragma unroll
            for (int j = 0; j < 8; j++)
              #pragma unroll
              for (int dx = 0; dx < 3; dx++)
                t[j] = fmaf(kw[dy*3+dx], w[j+dx+2], t[j]);
          }
          int gy = oy0 + iy - 1;
          bool rin = (gy >= 0 && gy < HH);
          #pragma unroll
          for (int j = 0; j < 8; j++) {
            int ix = x0 + j;
            if (ix < 66) {
              int gx = ox0 + ix - 1;
              tbuf[iy][ix] = (rin && gx >= 0 && gx < WW) ? t[j] : 0.f;
            }
          }
        }
      }
      __syncthreads();
      {
        float kw[9];
        #pragma unroll
        for (int k = 0; k < 9; k++) kw[k] = mu * Kw[ch*9 + k];
        #pragma unroll
        for (int dy = 0; dy < 3; dy++) {
          const float* row = &tbuf[sy+2-dy][sx0];
          float4 r0 = *(const float4*)(row);
          float4 r1 = *(const float4*)(row+4);
          float4 r2 = *(const float4*)(row+8);
          float w[12] = {r0.x,r0.y,r0.z,r0.w, r1.x,r1.y,r1.z,r1.w, r2.x,r2.y,r2.z,r2.w};
          #pragma unroll
          for (int k = 0; k < 8; k++)
            #pragma unroll
            for (int dx = 0; dx < 3; dx++)
              accv[k] = fmaf(kw[dy*3+dx], w[k+2-dx], accv[k]);
        }
      }
      __syncthreads();
    }
  }

  // ---- epilogue ----
  const int gy = oy0 + sy, gx0 = ox0 + sx0;
  float part = 0.f;
  if (MODE == 0) {
    #pragma unroll
    for (int k = 0; k < 8; k++) {
      size_t idx = (size_t)bimg*IMG + gy*WW + gx0 + k;
      float rv = accv[k] - rhs[idx];
      outQ[idx] = rv;
      outP[idx] = -rv;
      part += rv*rv;
    }
  } else {
    #pragma unroll
    for (int k = 0; k < 8; k++) {
      size_t idx = (size_t)bimg*IMG + gy*WW + gx0 + k;
      float pv = ssrc[sy+4][sx0+4+k];
      outQ[idx] = accv[k];
      part += pv * accv[k];
    }
  }
  atomic_block_sum(part, red, &acc[bimg]);
}

// ---------------- CG axpy update ---------------------------------------------------
__launch_bounds__(256)
__global__ void k_upd(float* __restrict__ xk, float* __restrict__ r,
                      const float* __restrict__ p, const float* __restrict__ q,
                      const float* __restrict__ num, const float* __restrict__ den,
                      float* __restrict__ rtrOut) {
  __shared__ float red[4];
  const int tid = threadIdx.x;
  const int bimg = blockIdx.x >> 8;
  const size_t idx4 = (size_t)blockIdx.x * 256 + tid;
  const float al = num[bimg] / den[bimg];
  float4 xv = ((const float4*)xk)[idx4];
  float4 pv = ((const float4*)p)[idx4];
  float4 rv = ((const float4*)r)[idx4];
  float4 qv = ((const float4*)q)[idx4];
  xv.x += al*pv.x; xv.y += al*pv.y; xv.z += al*pv.z; xv.w += al*pv.w;
  rv.x += al*qv.x; rv.y += al*qv.y; rv.z += al*qv.z; rv.w += al*qv.w;
  ((float4*)xk)[idx4] = xv;
  ((float4*)r)[idx4] = rv;
  float part = rv.x*rv.x + rv.y*rv.y + rv.z*rv.z + rv.w*rv.w;
  atomic_block_sum(part, red, &rtrOut[bimg]);
}

__launch_bounds__(256)
__global__ void k_final(const float* __restrict__ xk, const float* __restrict__ p,
                        const float* __restrict__ num, const float* __restrict__ den,
                        float* __restrict__ out) {
  const int tid = threadIdx.x;
  const int bimg = blockIdx.x >> 8;
  const size_t idx4 = (size_t)blockIdx.x * 256 + tid;
  const float al = num[bimg] / den[bimg];
  float4 xv = ((const float4*)xk)[idx4];
  float4 pv = ((const float4*)p)[idx4];
  float4 o;
  o.x = xv.x + al*pv.x; o.y = xv.y + al*pv.y; o.z = xv.z + al*pv.z; o.w = xv.w + al*pv.w;
  ((float4*)out)[idx4] = o;
}

extern "C" void kernel_launch(void* const* d_in, const int* in_sizes, int n_in,
                              void* d_out, int out_size, void* d_ws, size_t ws_size,
                              hipStream_t stream) {
  const float* sino = (const float*)d_in[0];
  const float* x    = (const float*)d_in[1];
  const float* laam = (const float*)d_in[2];
  const float* miu  = (const float*)d_in[3];
  const float* Kw   = (const float*)d_in[4];
  const float* Ka   = (const float*)d_in[5];
  const float* W1   = (const float*)d_in[6];
  const float* b1   = (const float*)d_in[7];
  const float* W2   = (const float*)d_in[8];
  const float* b2   = (const float*)d_in[9];
  const float* W3   = (const float*)d_in[10];
  const float* b3   = (const float*)d_in[11];

  float* ws = (float*)d_ws;
  float* xk = ws;
  float* r  = ws + (size_t)NTOT;
  float* p0 = ws + 2*(size_t)NTOT;
  float* p1 = ws + 3*(size_t)NTOT;
  float* q  = ws + 4*(size_t)NTOT;
  float* G    = ws + 5*(size_t)NTOT;   // 81 (pad to 96)
  float* accb = G + 96;                // 96 floats: den[48], rtr[48]
  float* den = accb;
  float* rtr = accb + 48;
  ushort* w2pk = (ushort*)(accb + 96); // 9216 ushorts
  uint*   w1pk = (uint*)(w2pk + 9216); // 144
  uint*   b1pk = w1pk + 144;           // 16
  ushort* w3fr = (ushort*)(b1pk + 16); // 512 ushorts
  float* rhs = (float*)d_out;
  float* out = (float*)d_out;

  (void)hipMemsetAsync(accb, 0, 96*sizeof(float), stream);
  k_prep<<<1, 256, 0, stream>>>(Ka, Kw, miu, W1, b1, W2, W3, G, w2pk, w1pk, b1pk, w3fr);
  k_cnn<<<dim3(32,32,8), 512, 0, stream>>>(x, w2pk, w1pk, b1pk, w3fr, b2, b3, xk);
  k_rhs<<<dim3(16,16,8), 256, 0, stream>>>(sino, x, laam, miu, Ka, Kw, rhs);

  dim3 mg(8,16,8);
  k_M<0><<<mg,256,0,stream>>>(xk, nullptr, rhs, r, p0, G, Ka, Kw, miu, nullptr, nullptr, &rtr[0]);
  k_M<1><<<mg,256,0,stream>>>(p0, nullptr, nullptr, q, nullptr, G, Ka, Kw, miu, nullptr, nullptr, &den[0]);
  k_upd<<<2048,256,0,stream>>>(xk, r, p0, q, &rtr[0], &den[0], &rtr[8]);
  float* pcur = p0; float* pnext = p1;
  for (int i = 1; i <= 4; i++) {
    k_M<2><<<mg,256,0,stream>>>(r, pcur, nullptr, q, pnext, G, Ka, Kw, miu, &rtr[8*i], &rtr[8*(i-1)], &den[8*i]);
    k_upd<<<2048,256,0,stream>>>(xk, r, pnext, q, &rtr[8*i], &den[8*i], &rtr[8*(i+1)]);
    float* t = pcur; pcur = pnext; pnext = t;
  }
  k_M<2><<<mg,256,0,stream>>>(r, pcur, nullptr, q, pnext, G, Ka, Kw, miu, &rtr[40], &rtr[32], &den[40]);
  k_final<<<2048,256,0,stream>>>(xk, pnext, &rtr[40], &den[40], out);
}

// Round 6
// 467.295 us; speedup vs baseline: 4.8247x; 1.2574x over previous
//
#include <hip/hip_runtime.h>

#define HH 512
#define WW 512
#define BB 8
#define IMG (HH*WW)
#define NTOT (BB*IMG)

typedef float f32x4 __attribute__((ext_vector_type(4)));
typedef _Float16 half8 __attribute__((ext_vector_type(8)));

__device__ inline uint f2h2(float a, float b) {
  uint d; asm("v_cvt_pkrtz_f16_f32 %0, %1, %2" : "=v"(d) : "v"(a), "v"(b)); return d;
}
__device__ inline uint pkfma(uint a, uint b, uint c) {
  uint d; asm("v_pk_fma_f16 %0, %1, %2, %3" : "=v"(d) : "v"(a), "v"(b), "v"(c)); return d;
}
__device__ inline uint pkmax0(uint a) {
  uint d, z = 0u; asm("v_pk_max_f16 %0, %1, %2" : "=v"(d) : "v"(a), "v"(z)); return d;
}

__device__ inline void atomic_block_sum(float part, float* red, float* dst) {
  for (int off = 32; off > 0; off >>= 1) part += __shfl_down(part, off, 64);
  int lane = threadIdx.x & 63, w = threadIdx.x >> 6;
  if (lane == 0) red[w] = part;
  __syncthreads();
  if (threadIdx.x == 0) atomicAdd(dst, red[0] + red[1] + red[2] + red[3]);
}

// ---------------- prep: G stencil + fp16 weight packing ----------------------------
__global__ void k_prep(const float* __restrict__ Ka, const float* __restrict__ Kw,
                       const float* __restrict__ miu,
                       const float* __restrict__ W1, const float* __restrict__ b1,
                       const float* __restrict__ W2, const float* __restrict__ W3,
                       float* __restrict__ G, ushort* __restrict__ w2pk,
                       uint* __restrict__ w1pk, uint* __restrict__ b1pk,
                       ushort* __restrict__ w3fr) {
  int tid = threadIdx.x;
  if (tid < 81) {
    int oy = tid / 9 - 4, ox = tid % 9 - 4;
    float mu = miu[0];
    float ga = 0.f;
    for (int dy = 0; dy < 5; dy++)
      for (int dx = 0; dx < 5; dx++) {
        int ey = dy + oy, ex = dx + ox;
        if (ey >= 0 && ey < 5 && ex >= 0 && ex < 5) ga += Ka[dy*5+dx] * Ka[ey*5+ex];
      }
    float gw = 0.f;
    if (oy >= -2 && oy <= 2 && ox >= -2 && ox <= 2) {
      for (int ch = 0; ch < 4; ch++)
        for (int dy = 0; dy < 3; dy++)
          for (int dx = 0; dx < 3; dx++) {
            int ey = dy + oy, ex = dx + ox;
            if (ey >= 0 && ey < 3 && ex >= 0 && ex < 3)
              gw += Kw[ch*9 + dy*3+dx] * Kw[ch*9 + ey*3+ex];
          }
    }
    G[tid] = ga + mu * gw;
  }
  for (int i = tid; i < 9216; i += 256) {
    int j = i & 7, l = (i >> 3) & 63, f = i >> 9;
    int t5 = f >> 1, h = f & 1;
    int co = 16*h + (l & 15), ci = 8*(l >> 4) + j;
    w2pk[i] = (ushort)(f2h2(W2[(co*32 + ci)*9 + t5], 0.f) & 0xffffu);
  }
  if (tid < 144) {
    int cp = tid / 9, t = tid % 9;
    w1pk[tid] = f2h2(W1[(2*cp)*9 + t], W1[(2*cp+1)*9 + t]);
  }
  if (tid < 16) b1pk[tid] = f2h2(b1[2*tid], b1[2*tid+1]);
  for (int i = tid; i < 512; i += 256) {
    int j = i & 7, l = i >> 3;
    int tap = l & 15, ch = 8*(l >> 4) + j;
    w3fr[i] = (tap < 9) ? (ushort)(f2h2(W3[ch*9 + tap], 0.f) & 0xffffu) : (ushort)0;
  }
}

// ---------------- fused CNN: xk = cnn(x), fp16/MFMA --------------------------------
// h1u: [row][kg*88 + px*4 + cl], row stride 352 uints (Tlds aliased on top after conv2)
// h2u: [row][slice*76 + px*4 + sub], row stride 304 uints
__launch_bounds__(512)
__global__ void k_cnn(const float* __restrict__ x,
                      const ushort* __restrict__ w2pk, const uint* __restrict__ w1pk,
                      const uint* __restrict__ b1pk, const ushort* __restrict__ w3fr,
                      const float* __restrict__ b2, const float* __restrict__ b3,
                      float* __restrict__ xk) {
  __shared__ __align__(16) uint  xs_h2[528];        // 22 rows x 24 cols, half2-bcast
  __shared__ __align__(16) uint  h1u[7040];         // 20 x 352
  __shared__ __align__(16) uint  h2u[5472];         // 18 x 304

  const int tid = threadIdx.x;
  const int bimg = blockIdx.z;
  const int oy0 = blockIdx.y * 16, ox0 = blockIdx.x * 16;
  const float* xim = x + (size_t)bimg * IMG;

  for (int i = tid; i < 528; i += 512) {
    int ly = i / 24, lx = i % 24;
    int gy = oy0 + ly - 3, gx = ox0 + lx - 4;
    float v = 0.f;
    if ((unsigned)gy < HH && (unsigned)gx < WW) v = xim[gy*WW + gx];
    xs_h2[i] = f2h2(v, v);
  }
  __syncthreads();

  // ---- conv1 ----
  {
    const int cp = tid & 15;
    const int sg = tid >> 4;
    uint w1r[9];
    #pragma unroll
    for (int k = 0; k < 9; k++) w1r[k] = w1pk[cp*9 + k];
    const uint b1v = b1pk[cp];
    const int kg = cp >> 2, cl = cp & 3;
    #pragma unroll 1
    for (int s = sg; s < 100; s += 32) {
      int row = s / 5, st = s - 5*row;
      int px0 = st * 4;
      uint acc0 = b1v, acc1 = b1v, acc2 = b1v, acc3 = b1v;
      #pragma unroll
      for (int ky = 0; ky < 3; ky++) {
        int base = (row + ky) * 24 + px0;
        uint4 xa = *(const uint4*)&xs_h2[base];
        uint4 xb = *(const uint4*)&xs_h2[base + 4];
        uint xu[8] = {xa.x, xa.y, xa.z, xa.w, xb.x, xb.y, xb.z, xb.w};
        #pragma unroll
        for (int kx = 0; kx < 3; kx++) {
          uint w = w1r[ky*3 + kx];
          acc0 = pkfma(w, xu[1 + kx], acc0);
          acc1 = pkfma(w, xu[2 + kx], acc1);
          acc2 = pkfma(w, xu[3 + kx], acc2);
          acc3 = pkfma(w, xu[4 + kx], acc3);
        }
      }
      int Y = oy0 + row - 2;
      bool rin = (unsigned)Y < HH;
      int ob = row*352 + kg*88 + px0*4 + cl;
      #pragma unroll
      for (int i = 0; i < 4; i++) {
        int X = ox0 + px0 + i - 2;
        uint v = (rin && (unsigned)X < WW) ?
                 pkmax0(i == 0 ? acc0 : (i == 1 ? acc1 : (i == 2 ? acc2 : acc3))) : 0u;
        h1u[ob + i*4] = v;
      }
    }
  }
  __syncthreads();

  // ---- conv2 via MFMA f16 ----
  const int wv = tid >> 6, lane = tid & 63;
  const int nn = lane & 15, kg = lane >> 4;
  {
    half8 afr[9][2];
    #pragma unroll
    for (int t5 = 0; t5 < 9; t5++) {
      afr[t5][0] = ((const half8*)w2pk)[(t5*2 + 0)*64 + lane];
      afr[t5][1] = ((const half8*)w2pk)[(t5*2 + 1)*64 + lane];
    }
    float b2A[4], b2B[4];
    #pragma unroll
    for (int j = 0; j < 4; j++) { b2A[j] = b2[4*kg + j]; b2B[j] = b2[16 + 4*kg + j]; }

    #pragma unroll 1
    for (int t = wv; t < 27; t += 8) {
      int rp = t / 3, cs = t - 3*rp;
      int tx0 = (cs == 2) ? 10 : (cs << 3);
      int brow = 2*rp + (nn >> 3);
      int bcol = tx0 + (nn & 7);
      f32x4 accA = {0.f,0.f,0.f,0.f}, accB = {0.f,0.f,0.f,0.f};
      #pragma unroll
      for (int ky = 0; ky < 3; ky++)
        #pragma unroll
        for (int kx = 0; kx < 3; kx++) {
          const half8 bfr = *(const half8*)&h1u[(brow+ky)*352 + kg*88 + (bcol+kx)*4];
          accA = __builtin_amdgcn_mfma_f32_16x16x32_f16(afr[ky*3+kx][0], bfr, accA, 0, 0, 0);
          accB = __builtin_amdgcn_mfma_f32_16x16x32_f16(afr[ky*3+kx][1], bfr, accB, 0, 0, 0);
        }
      int gy = oy0 + brow - 1, gx = ox0 + bcol - 1;
      bool inb = ((unsigned)gy < HH) && ((unsigned)gx < WW);
      float v0 = inb ? fmaxf(accA[0] + b2A[0], 0.f) : 0.f;
      float v1 = inb ? fmaxf(accA[1] + b2A[1], 0.f) : 0.f;
      float v2 = inb ? fmaxf(accA[2] + b2A[2], 0.f) : 0.f;
      float v3 = inb ? fmaxf(accA[3] + b2A[3], 0.f) : 0.f;
      uint2 uA = make_uint2(f2h2(v0, v1), f2h2(v2, v3));
      v0 = inb ? fmaxf(accB[0] + b2B[0], 0.f) : 0.f;
      v1 = inb ? fmaxf(accB[1] + b2B[1], 0.f) : 0.f;
      v2 = inb ? fmaxf(accB[2] + b2B[2], 0.f) : 0.f;
      v3 = inb ? fmaxf(accB[3] + b2B[3], 0.f) : 0.f;
      uint2 uB = make_uint2(f2h2(v0, v1), f2h2(v2, v3));
      int base = brow*304 + bcol*4 + (kg & 1)*2;
      *(uint2*)&h2u[base + (kg >> 1)*76]       = uA;
      *(uint2*)&h2u[base + (2 + (kg >> 1))*76] = uB;
    }
  }
  __syncthreads();

  // ---- conv3 stage 1 via MFMA (Tlds aliased onto h1u, which is dead) ----
  float* Tlds = (float*)h1u;   // needs 3240 floats <= 7040 uints
  {
    const half8 w3f = ((const half8*)w3fr)[lane];
    const int tap = nn;
    #pragma unroll 1
    for (int t = wv; t < 27; t += 8) {
      int rp = t / 3, cs = t - 3*rp;
      int tx0 = (cs == 2) ? 10 : (cs << 3);
      int ay = 2*rp + (nn >> 3);
      int ax = tx0 + (nn & 7);
      const half8 afrag = *(const half8*)&h2u[ay*304 + kg*76 + ax*4];
      f32x4 z = {0.f,0.f,0.f,0.f};
      f32x4 T4 = __builtin_amdgcn_mfma_f32_16x16x32_f16(afrag, w3f, z, 0, 0, 0);
      if (tap < 9) {
        int ty = 2*rp + (kg >> 1);
        int txb = tx0 + 4*(kg & 1);
        float* dst = &Tlds[ty*180 + tap*20 + txb];
        if (cs == 2) {
          dst[0] = T4[0]; dst[1] = T4[1]; dst[2] = T4[2]; dst[3] = T4[3];
        } else {
          *(f32x4*)dst = T4;
        }
      }
    }
  }
  __syncthreads();

  // ---- conv3 gather + residual ----
  if (tid < 256) {
    int oy = tid >> 4, ox = tid & 15;
    float s = b3[0] + xim[(size_t)(oy0+oy)*WW + ox0 + ox];
    #pragma unroll
    for (int ky = 0; ky < 3; ky++)
      #pragma unroll
      for (int kx = 0; kx < 3; kx++)
        s += Tlds[(oy+ky)*180 + (3*ky+kx)*20 + (ox+kx)];
    xk[(size_t)bimg*IMG + (size_t)(oy0+oy)*WW + ox0 + ox] = s;
  }
}

// ---------------- rhs = ATop(sino) + miu * WTop(softthresh(Wop(x))) ----------------
__launch_bounds__(256)
__global__ void k_rhs(const float* __restrict__ sino, const float* __restrict__ x,
                      const float* __restrict__ laam, const float* __restrict__ miu,
                      const float* __restrict__ Ka, const float* __restrict__ Kw,
                      float* __restrict__ rhs) {
  __shared__ float xs[36][37];
  __shared__ float ss[36][37];
  __shared__ float dz[4][34][35];
  __shared__ float kas[25], kws[36];
  int tid = threadIdx.x;
  int bimg = blockIdx.z;
  int oy0 = blockIdx.y*32, ox0 = blockIdx.x*32;
  const float* xim = x + (size_t)bimg*IMG;
  const float* sim = sino + (size_t)bimg*IMG;
  if (tid < 25) kas[tid] = Ka[tid];
  if (tid < 36) kws[tid] = Kw[tid];
  float lam = laam[0], mu = miu[0];
  for (int i = tid; i < 1296; i += 256) {
    int y = i/36, xx = i%36;
    int gy = oy0 + y - 2, gx = ox0 + xx - 2;
    bool in = (gy >= 0 && gy < HH && gx >= 0 && gx < WW);
    xs[y][xx] = in ? xim[gy*WW+gx] : 0.f;
    ss[y][xx] = in ? sim[gy*WW+gx] : 0.f;
  }
  __syncthreads();
  for (int i = tid; i < 1156; i += 256) {
    int dy = i/34, dx = i%34;
    int gy = oy0 + dy - 1, gx = ox0 + dx - 1;
    bool in = (gy >= 0 && gy < HH && gx >= 0 && gx < WW);
    #pragma unroll
    for (int ch = 0; ch < 4; ch++) {
      float v = 0.f;
      if (in) {
        float wu = 0.f;
        #pragma unroll
        for (int e = 0; e < 9; e++) wu = fmaf(kws[ch*9+e], xs[dy + e/3][dx + e%3], wu);
        v = fmaxf(wu - lam, 0.f) - fmaxf(-wu - lam, 0.f);
      }
      dz[ch][dy][dx] = v;
    }
  }
  __syncthreads();
  for (int i = tid; i < 1024; i += 256) {
    int oy = i/32, ox = i%32;
    float qa = 0.f;
    #pragma unroll
    for (int d = 0; d < 25; d++) qa = fmaf(kas[d], ss[oy + 4 - d/5][ox + 4 - d%5], qa);
    float wt = 0.f;
    #pragma unroll
    for (int ch = 0; ch < 4; ch++)
      #pragma unroll
      for (int d = 0; d < 9; d++)
        wt = fmaf(kws[ch*9+d], dz[ch][oy + 2 - d/3][ox + 2 - d%3], wt);
    rhs[(size_t)bimg*IMG + (oy0+oy)*WW + ox0+ox] = qa + mu*wt;
  }
}

// ---------------- shared M-apply body ----------------------------------------------
__device__ __forceinline__ void apply_M(float (*ssrc)[76], float (*tbuf)[68],
    const float* Gs, const float* __restrict__ Ka, const float* __restrict__ Kw,
    float mu, bool edgeB, int tid, int oy0, int ox0, float* accv) {
  const int sy = tid >> 3, sx0 = (tid & 7) * 8;
  #pragma unroll
  for (int k = 0; k < 8; k++) accv[k] = 0.f;

  if (!edgeB) {
    #pragma unroll 1
    for (int oyy = 0; oyy < 9; oyy++) {
      float g[9];
      #pragma unroll
      for (int t = 0; t < 9; t++) g[t] = Gs[oyy*9+t];
      const float* row = &ssrc[sy+oyy][sx0];
      float4 r0 = *(const float4*)(row);
      float4 r1 = *(const float4*)(row+4);
      float4 r2 = *(const float4*)(row+8);
      float4 r3 = *(const float4*)(row+12);
      float v[16] = {r0.x,r0.y,r0.z,r0.w, r1.x,r1.y,r1.z,r1.w,
                     r2.x,r2.y,r2.z,r2.w, r3.x,r3.y,r3.z,r3.w};
      #pragma unroll
      for (int k = 0; k < 8; k++) {
        float a = accv[k];
        #pragma unroll
        for (int t = 0; t < 9; t++) a = fmaf(g[t], v[k+t], a);
        accv[k] = a;
      }
    }
  } else {
    {
      float ka[25];
      #pragma unroll
      for (int k = 0; k < 25; k++) ka[k] = Ka[k];
      #pragma unroll 1
      for (int item = tid; item < 324; item += 256) {
        int iy = item / 9, c = item - 9*iy;
        int x0 = c*8;
        float t[8];
        #pragma unroll
        for (int j = 0; j < 8; j++) t[j] = 0.f;
        #pragma unroll
        for (int dy = 0; dy < 5; dy++) {
          const float* row = &ssrc[iy+dy][x0];
          float4 r0 = *(const float4*)(row);
          float4 r1 = *(const float4*)(row+4);
          float4 r2 = *(const float4*)(row+8);
          float w[12] = {r0.x,r0.y,r0.z,r0.w, r1.x,r1.y,r1.z,r1.w, r2.x,r2.y,r2.z,r2.w};
          #pragma unroll
          for (int j = 0; j < 8; j++)
            #pragma unroll
            for (int dx = 0; dx < 5; dx++)
              t[j] = fmaf(ka[dy*5+dx], w[j+dx], t[j]);
        }
        int gy = oy0 + iy - 2;
        bool rin = (gy >= 0 && gy < HH);
        #pragma unroll
        for (int j = 0; j < 8; j++) {
          int ix = x0 + j;
          if (ix < 68) {
            int gx = ox0 + ix - 2;
            tbuf[iy][ix] = (rin && gx >= 0 && gx < WW) ? t[j] : 0.f;
          }
        }
      }
    }
    __syncthreads();
    {
      float ka[25];
      #pragma unroll
      for (int k = 0; k < 25; k++) ka[k] = Ka[k];
      #pragma unroll
      for (int dy = 0; dy < 5; dy++) {
        const float* row = &tbuf[sy+4-dy][sx0];
        float4 r0 = *(const float4*)(row);
        float4 r1 = *(const float4*)(row+4);
        float4 r2 = *(const float4*)(row+8);
        float w[12] = {r0.x,r0.y,r0.z,r0.w, r1.x,r1.y,r1.z,r1.w, r2.x,r2.y,r2.z,r2.w};
        #pragma unroll
        for (int k = 0; k < 8; k++)
          #pragma unroll
          for (int dx = 0; dx < 5; dx++)
            accv[k] = fmaf(ka[dy*5+dx], w[k+4-dx], accv[k]);
      }
    }
    __syncthreads();
    #pragma unroll 1
    for (int ch = 0; ch < 4; ch++) {
      {
        float kw[9];
        #pragma unroll
        for (int k = 0; k < 9; k++) kw[k] = Kw[ch*9 + k];
        #pragma unroll 1
        for (int item = tid; item < 306; item += 256) {
          int iy = item / 9, c = item - 9*iy;
          int x0 = c*8;
          float t[8];
          #pragma unroll
          for (int j = 0; j < 8; j++) t[j] = 0.f;
          #pragma unroll
          for (int dy = 0; dy < 3; dy++) {
            const float* row = &ssrc[iy+dy+2][x0];
            float4 r0 = *(const float4*)(row);
            float4 r1 = *(const float4*)(row+4);
            float4 r2 = *(const float4*)(row+8);
            float w[12] = {r0.x,r0.y,r0.z,r0.w, r1.x,r1.y,r1.z,r1.w, r2.x,r2.y,r2.z,r2.w};
            #pragma unroll
            for (int j = 0; j < 8; j++)
              #pragma unroll
              for (int dx = 0; dx < 3; dx++)
                t[j] = fmaf(kw[dy*3+dx], w[j+dx+2], t[j]);
          }
          int gy = oy0 + iy - 1;
          bool rin = (gy >= 0 && gy < HH);
          #pragma unroll
          for (int j = 0; j < 8; j++) {
            int ix = x0 + j;
            if (ix < 66) {
              int gx = ox0 + ix - 1;
              tbuf[iy][ix] = (rin && gx >= 0 && gx < WW) ? t[j] : 0.f;
            }
          }
        }
      }
      __syncthreads();
      {
        float kw[9];
        #pragma unroll
        for (int k = 0; k < 9; k++) kw[k] = mu * Kw[ch*9 + k];
        #pragma unroll
        for (int dy = 0; dy < 3; dy++) {
          const float* row = &tbuf[sy+2-dy][sx0];
          float4 r0 = *(const float4*)(row);
          float4 r1 = *(const float4*)(row+4);
          float4 r2 = *(const float4*)(row+8);
          float w[12] = {r0.x,r0.y,r0.z,r0.w, r1.x,r1.y,r1.z,r1.w, r2.x,r2.y,r2.z,r2.w};
          #pragma unroll
          for (int k = 0; k < 8; k++)
            #pragma unroll
            for (int dx = 0; dx < 3; dx++)
              accv[k] = fmaf(kw[dy*3+dx], w[k+2-dx], accv[k]);
        }
      }
      __syncthreads();
    }
  }
}

// ---------------- k_M: MODE 0 (init r,p + rtr), MODE 1 (q0 + den/rq/qq), MODE 2 ----
template<int MODE>
__launch_bounds__(256)
__global__ void k_M(const float* __restrict__ srcA, const float* __restrict__ srcB,
                    const float* __restrict__ rhs,
                    float* __restrict__ outQ, float* __restrict__ outP,
                    const float* __restrict__ G,
                    const float* __restrict__ Ka, const float* __restrict__ Kw,
                    const float* __restrict__ miu,
                    const float* __restrict__ beN, const float* __restrict__ beD,
                    float* __restrict__ acc, float* __restrict__ rqOut,
                    float* __restrict__ qqOut) {
  __shared__ __align__(16) float ssrc[40][76];
  __shared__ __align__(16) float tbuf[36][68];
  __shared__ float Gs[81];
  __shared__ float red[12];
  const int tid = threadIdx.x;
  const int bimg = blockIdx.z;
  const int oy0 = blockIdx.y*32, ox0 = blockIdx.x*64;
  const bool edgeB = (blockIdx.y == 0) || (blockIdx.y == gridDim.y-1) ||
                     (blockIdx.x == 0) || (blockIdx.x == gridDim.x-1);
  if (tid < 81) Gs[tid] = G[tid];
  const float mu = miu[0];
  float be = 0.f;
  if (MODE == 2) be = beN[bimg] / beD[bimg];
  const float* sA = srcA + (size_t)bimg*IMG;
  const float* sB = (MODE == 2) ? srcB + (size_t)bimg*IMG : nullptr;

  for (int i = tid; i < 40*76; i += 256) {
    int ly = i/76, lx = i%76;
    int gy = oy0 + ly - 4, gx = ox0 + lx - 4;
    bool in = (lx < 72) && (gy >= 0 && gy < HH && gx >= 0 && gx < WW);
    float v = 0.f;
    if (MODE == 2) {
      if (in) {
        v = -sA[gy*WW+gx] + be * sB[gy*WW+gx];
        if (ly >= 4 && ly < 36 && lx >= 4 && lx < 68)
          outP[(size_t)bimg*IMG + gy*WW + gx] = v;
      }
    } else {
      if (in) v = sA[gy*WW+gx];
    }
    ssrc[ly][lx] = v;
  }
  __syncthreads();

  float accv[8];
  apply_M(ssrc, tbuf, Gs, Ka, Kw, mu, edgeB, tid, oy0, ox0, accv);

  const int sy = tid >> 3, sx0 = (tid & 7) * 8;
  const int gy = oy0 + sy, gx0 = ox0 + sx0;
  if (MODE == 0) {
    float part = 0.f;
    #pragma unroll
    for (int k = 0; k < 8; k++) {
      size_t idx = (size_t)bimg*IMG + gy*WW + gx0 + k;
      float rv = accv[k] - rhs[idx];
      outQ[idx] = rv;
      outP[idx] = -rv;
      part += rv*rv;
    }
    atomic_block_sum(part, red, &acc[bimg]);
  } else if (MODE == 1) {
    float pq = 0.f, qq = 0.f;
    #pragma unroll
    for (int k = 0; k < 8; k++) {
      size_t idx = (size_t)bimg*IMG + gy*WW + gx0 + k;
      float pv = ssrc[sy+4][sx0+4+k];
      float qv = accv[k];
      outQ[idx] = qv;
      pq += pv * qv;
      qq += qv * qv;
    }
    for (int off = 32; off > 0; off >>= 1) {
      pq += __shfl_down(pq, off, 64);
      qq += __shfl_down(qq, off, 64);
    }
    int lane = tid & 63, w = tid >> 6;
    if (lane == 0) { red[w*2] = pq; red[w*2+1] = qq; }
    __syncthreads();
    if (tid == 0) {
      float A = red[0]+red[2]+red[4]+red[6];
      float Q = red[1]+red[3]+red[5]+red[7];
      atomicAdd(&acc[bimg], A);
      atomicAdd(&rqOut[bimg], -A);
      atomicAdd(&qqOut[bimg], Q);
    }
  } else {
    float part = 0.f;
    #pragma unroll
    for (int k = 0; k < 8; k++) {
      size_t idx = (size_t)bimg*IMG + gy*WW + gx0 + k;
      float pv = ssrc[sy+4][sx0+4+k];
      outQ[idx] = accv[k];
      part += pv * accv[k];
    }
    atomic_block_sum(part, red, &acc[bimg]);
  }
}

// ---------------- fused CG iteration (scalar recurrence) ---------------------------
// al = rtr/den; x += al p; r_new = r + al q; rtr_new = rtr + 2 al <r,q> + al^2 <q,q>;
// be = rtr_new/rtr; p_new = -r_new + be p; q_new = M p_new; reduce den/rq/qq.
__launch_bounds__(256)
__global__ void k_it(float* __restrict__ xk,
                     const float* __restrict__ rold, float* __restrict__ rnew,
                     const float* __restrict__ pold, float* __restrict__ pnew,
                     const float* __restrict__ qold, float* __restrict__ qnew,
                     const float* __restrict__ G,
                     const float* __restrict__ Ka, const float* __restrict__ Kw,
                     const float* __restrict__ miu,
                     float* __restrict__ scal, int it) {
  __shared__ __align__(16) float ssrc[40][76];
  __shared__ __align__(16) float tbuf[36][68];
  __shared__ float rlds[2048];
  __shared__ float Gs[81];
  __shared__ float red[12];
  const int tid = threadIdx.x;
  const int bimg = blockIdx.z;
  const int oy0 = blockIdx.y*32, ox0 = blockIdx.x*64;
  const bool edgeB = (blockIdx.y == 0) || (blockIdx.y == gridDim.y-1) ||
                     (blockIdx.x == 0) || (blockIdx.x == gridDim.x-1);
  if (tid < 81) Gs[tid] = G[tid];
  const float mu = miu[0];
  const float den_p = scal[       (it-1)*8 + bimg];
  const float rq_p  = scal[ 48 + (it-1)*8 + bimg];
  const float qq_p  = scal[ 96 + (it-1)*8 + bimg];
  const float rtr_p = scal[144 + (it-1)*8 + bimg];
  const float al = rtr_p / den_p;
  const float rtr_c = fmaf(al, fmaf(al, qq_p, 2.f*rq_p), rtr_p);
  const float be = rtr_c / rtr_p;
  if (tid == 0) scal[144 + it*8 + bimg] = rtr_c;
  const size_t ib = (size_t)bimg*IMG;

  for (int i = tid; i < 40*76; i += 256) {
    int ly = i/76, lx = i%76;
    int gy = oy0 + ly - 4, gx = ox0 + lx - 4;
    bool in = (lx < 72) && (gy >= 0 && gy < HH && gx >= 0 && gx < WW);
    float v = 0.f;
    if (in) {
      size_t g = ib + (size_t)gy*WW + gx;
      float pg = pold[g];
      float rn = fmaf(al, qold[g], rold[g]);
      v = fmaf(be, pg, -rn);
      if (ly >= 4 && ly < 36 && lx >= 4 && lx < 68) {
        pnew[g] = v;
        rnew[g] = rn;
        xk[g] = fmaf(al, pg, xk[g]);
        rlds[(ly-4)*64 + (lx-4)] = rn;
      }
    }
    ssrc[ly][lx] = v;
  }
  __syncthreads();

  float accv[8];
  apply_M(ssrc, tbuf, Gs, Ka, Kw, mu, edgeB, tid, oy0, ox0, accv);

  const int sy = tid >> 3, sx0 = (tid & 7) * 8;
  const int gy = oy0 + sy, gx0 = ox0 + sx0;
  float s_den = 0.f, s_rq = 0.f, s_qq = 0.f;
  #pragma unroll
  for (int k = 0; k < 8; k++) {
    size_t idx = ib + (size_t)gy*WW + gx0 + k;
    float qv = accv[k];
    float pv = ssrc[sy+4][sx0+4+k];
    float rv = rlds[sy*64 + sx0 + k];
    qnew[idx] = qv;
    s_den += pv*qv;
    s_rq  += rv*qv;
    s_qq  += qv*qv;
  }
  for (int off = 32; off > 0; off >>= 1) {
    s_den += __shfl_down(s_den, off, 64);
    s_rq  += __shfl_down(s_rq,  off, 64);
    s_qq  += __shfl_down(s_qq,  off, 64);
  }
  int lane = tid & 63, w = tid >> 6;
  if (lane == 0) { red[w*3] = s_den; red[w*3+1] = s_rq; red[w*3+2] = s_qq; }
  __syncthreads();
  if (tid == 0) {
    atomicAdd(&scal[       it*8 + bimg], red[0]+red[3]+red[6]+red[9]);
    atomicAdd(&scal[ 48 + it*8 + bimg], red[1]+red[4]+red[7]+red[10]);
    atomicAdd(&scal[ 96 + it*8 + bimg], red[2]+red[5]+red[8]+red[11]);
  }
}

// ---------------- fallback axpy (used only if workspace too small) -----------------
__launch_bounds__(256)
__global__ void k_upd(float* __restrict__ xk, float* __restrict__ r,
                      const float* __restrict__ p, const float* __restrict__ q,
                      const float* __restrict__ num, const float* __restrict__ den,
                      float* __restrict__ rtrOut) {
  __shared__ float red[4];
  const int tid = threadIdx.x;
  const int bimg = blockIdx.x >> 8;
  const size_t idx4 = (size_t)blockIdx.x * 256 + tid;
  const float al = num[bimg] / den[bimg];
  float4 xv = ((const float4*)xk)[idx4];
  float4 pv = ((const float4*)p)[idx4];
  float4 rv = ((const float4*)r)[idx4];
  float4 qv = ((const float4*)q)[idx4];
  xv.x += al*pv.x; xv.y += al*pv.y; xv.z += al*pv.z; xv.w += al*pv.w;
  rv.x += al*qv.x; rv.y += al*qv.y; rv.z += al*qv.z; rv.w += al*qv.w;
  ((float4*)xk)[idx4] = xv;
  ((float4*)r)[idx4] = rv;
  float part = rv.x*rv.x + rv.y*rv.y + rv.z*rv.z + rv.w*rv.w;
  atomic_block_sum(part, red, &rtrOut[bimg]);
}

__launch_bounds__(256)
__global__ void k_final(const float* __restrict__ xk, const float* __restrict__ p,
                        const float* __restrict__ num, const float* __restrict__ den,
                        float* __restrict__ out) {
  const int tid = threadIdx.x;
  const int bimg = blockIdx.x >> 8;
  const size_t idx4 = (size_t)blockIdx.x * 256 + tid;
  const float al = num[bimg] / den[bimg];
  float4 xv = ((const float4*)xk)[idx4];
  float4 pv = ((const float4*)p)[idx4];
  float4 o;
  o.x = xv.x + al*pv.x; o.y = xv.y + al*pv.y; o.z = xv.z + al*pv.z; o.w = xv.w + al*pv.w;
  ((float4*)out)[idx4] = o;
}

extern "C" void kernel_launch(void* const* d_in, const int* in_sizes, int n_in,
                              void* d_out, int out_size, void* d_ws, size_t ws_size,
                              hipStream_t stream) {
  const float* sino = (const float*)d_in[0];
  const float* x    = (const float*)d_in[1];
  const float* laam = (const float*)d_in[2];
  const float* miu  = (const float*)d_in[3];
  const float* Kw   = (const float*)d_in[4];
  const float* Ka   = (const float*)d_in[5];
  const float* W1   = (const float*)d_in[6];
  const float* b1   = (const float*)d_in[7];
  const float* W2   = (const float*)d_in[8];
  const float* b2   = (const float*)d_in[9];
  const float* W3   = (const float*)d_in[10];
  const float* b3   = (const float*)d_in[11];

  const bool fused = ws_size >= (size_t)6*NTOT*4 + 65536;
  float* ws = (float*)d_ws;
  const size_t nb = fused ? 6 : 5;
  float* tail = ws + nb*(size_t)NTOT;
  float* G    = tail;                  // 96
  float* scal = tail + 96;             // 192: den[48] rq[48] qq[48] rtr[48]
  ushort* w2pk = (ushort*)(scal + 192);
  uint*   w1pk = (uint*)(w2pk + 9216);
  uint*   b1pk = w1pk + 144;
  ushort* w3fr = (ushort*)(b1pk + 16);
  float* dout = (float*)d_out;

  (void)hipMemsetAsync(scal, 0, 192*sizeof(float), stream);
  k_prep<<<1, 256, 0, stream>>>(Ka, Kw, miu, W1, b1, W2, W3, G, w2pk, w1pk, b1pk, w3fr);

  float* xk = ws;
  k_cnn<<<dim3(32,32,8), 512, 0, stream>>>(x, w2pk, w1pk, b1pk, w3fr, b2, b3, xk);
  k_rhs<<<dim3(16,16,8), 256, 0, stream>>>(sino, x, laam, miu, Ka, Kw, dout);

  dim3 mg(8,16,8);
  if (fused) {
    float* rA = ws + (size_t)NTOT;
    float* rB = ws + 2*(size_t)NTOT;
    float* pA = ws + 3*(size_t)NTOT;
    float* pB = ws + 4*(size_t)NTOT;
    float* qB = ws + 5*(size_t)NTOT;
    float* qA = dout;   // rhs is dead after k_M<0>
    k_M<0><<<mg,256,0,stream>>>(xk, nullptr, dout, rA, pA, G, Ka, Kw, miu,
                                nullptr, nullptr, &scal[144], nullptr, nullptr);
    k_M<1><<<mg,256,0,stream>>>(pA, nullptr, nullptr, qA, nullptr, G, Ka, Kw, miu,
                                nullptr, nullptr, &scal[0], &scal[48], &scal[96]);
    float *rc=rA, *rn=rB, *pc=pA, *pn=pB, *qc=qA, *qn=qB;
    for (int it = 1; it <= 5; it++) {
      k_it<<<mg,256,0,stream>>>(xk, rc, rn, pc, pn, qc, qn, G, Ka, Kw, miu, scal, it);
      float* t;
      t = rc; rc = rn; rn = t;
      t = pc; pc = pn; pn = t;
      t = qc; qc = qn; qn = t;
    }
    k_final<<<2048,256,0,stream>>>(xk, pc, &scal[144+40], &scal[40], dout);
  } else {
    float* r  = ws + (size_t)NTOT;
    float* p0 = ws + 2*(size_t)NTOT;
    float* p1 = ws + 3*(size_t)NTOT;
    float* q  = ws + 4*(size_t)NTOT;
    k_M<0><<<mg,256,0,stream>>>(xk, nullptr, dout, r, p0, G, Ka, Kw, miu,
                                nullptr, nullptr, &scal[144], nullptr, nullptr);
    k_M<1><<<mg,256,0,stream>>>(p0, nullptr, nullptr, q, nullptr, G, Ka, Kw, miu,
                                nullptr, nullptr, &scal[0], &scal[48], &scal[96]);
    k_upd<<<2048,256,0,stream>>>(xk, r, p0, q, &scal[144], &scal[0], &scal[144+8]);
    float* pcur = p0; float* pnext = p1;
    for (int i = 1; i <= 4; i++) {
      k_M<2><<<mg,256,0,stream>>>(r, pcur, nullptr, q, pnext, G, Ka, Kw, miu,
                                  &scal[144+8*i], &scal[144+8*(i-1)], &scal[8*i],
                                  nullptr, nullptr);
      k_upd<<<2048,256,0,stream>>>(xk, r, pnext, q, &scal[144+8*i], &scal[8*i],
                                   &scal[144+8*(i+1)]);
      float* t = pcur; pcur = pnext; pnext = t;
    }
    k_M<2><<<mg,256,0,stream>>>(r, pcur, nullptr, q, pnext, G, Ka, Kw, miu,
                                &scal[144+40], &scal[144+32], &scal[40],
                                nullptr, nullptr);
    k_final<<<2048,256,0,stream>>>(xk, pnext, &scal[144+40], &scal[40], dout);
  }
}